// Round 1
// baseline (1407.344 us; speedup 1.0000x reference)
//
#include <hip/hip_runtime.h>
#include <hip/hip_bf16.h>
#include <math.h>

#define S_LEN 2048
#define BATCH 2
#define HDIM 1024
#define FDIM 3072
#define MAXK 819
#define MAXSPAN 30
#define NEGV -10000.0f

typedef __attribute__((ext_vector_type(8))) short short8;
typedef __attribute__((ext_vector_type(4))) float f32x4;
typedef __hip_bfloat16 hb;

__device__ __forceinline__ float gelu_f(float x) {
  return 0.5f * x * (1.0f + erff(x * 0.70710678118654752440f));
}

__device__ __forceinline__ unsigned short bf_bits(float x) {
  hb b = __float2bfloat16(x);
  return *reinterpret_cast<unsigned short*>(&b);
}
__device__ __forceinline__ float bf_back(unsigned short u) {
  hb b = *reinterpret_cast<hb*>(&u);
  return __bfloat162float(b);
}

__device__ __forceinline__ void gload16(const void* g, void* l) {
  __builtin_amdgcn_global_load_lds(
      (const __attribute__((address_space(1))) void*)g,
      (__attribute__((address_space(3))) void*)l, 16, 0, 0);
}

// ---------------------------------------------------------------------------
// bf16 MFMA GEMM, single-term, BK=128 (128 MFMA per barrier-pair).
// C[M,N] = act(A[M,K] @ B[N,K]^T + bias).  K multiple of 128.
// kspl>1: split-K — blockIdx.z = zb*kspl + zk; slice zk covers k in
// [zk*K, (zk+1)*K); C slice at blockIdx.z * sC (sum slices downstream).
// Swizzled LDS slots (16 x 16B per row), linear gload_lds dest.
// out_mode: 0 = f32, 1 = bf16.
// ---------------------------------------------------------------------------
__global__ __launch_bounds__(256) void gemm_fast1(
    const hb* __restrict__ A, const hb* __restrict__ B,
    const float* __restrict__ bias, void* __restrict__ Cv,
    int M, int N, int K, int lda, int ldb, int ldc,
    long long sA, long long sB, long long sC,
    int act, int out_mode, int kspl)
{
  const int zb = blockIdx.z / kspl, zk = blockIdx.z - zb * kspl;
  A += (long long)zb * sA + (long long)zk * K;
  B += (long long)zb * sB + (long long)zk * K;
  const long long cbase = (long long)blockIdx.z * sC;
  const int bm = blockIdx.y * 128, bn = blockIdx.x * 128;
  const int tid = threadIdx.x;
  const int lane = tid & 63;
  const int wv = tid >> 6, wr = wv >> 1, wc = wv & 1;
  const int lrow = lane & 15, lk = lane >> 4;
  __shared__ __align__(16) hb As[128 * 128];
  __shared__ __align__(16) hb Bs[128 * 128];

  const int srow = tid >> 4;          // 0..15
  const int sc8 = tid & 15;           // 16 slots of 8 bf16
  const int sslot = (sc8 - srow) & 15;  // inverse swizzle on global source

  f32x4 acc[4][4];
#pragma unroll
  for (int mi = 0; mi < 4; ++mi)
#pragma unroll
    for (int ni = 0; ni < 4; ++ni) acc[mi][ni] = (f32x4){0.f, 0.f, 0.f, 0.f};

  long long aoff[8], boff[8];
#pragma unroll
  for (int it = 0; it < 8; ++it) {
    int gm = bm + srow + it * 16; if (gm > M - 1) gm = M - 1;
    int gn = bn + srow + it * 16; if (gn > N - 1) gn = N - 1;
    aoff[it] = (long long)gm * lda + sslot * 8;
    boff[it] = (long long)gn * ldb + sslot * 8;
  }

  for (int k0 = 0; k0 < K; k0 += 128) {
#pragma unroll
    for (int it = 0; it < 8; ++it)
      gload16(A + aoff[it] + k0, &As[(tid + it * 256) * 8]);
#pragma unroll
    for (int it = 0; it < 8; ++it)
      gload16(B + boff[it] + k0, &Bs[(tid + it * 256) * 8]);
    __syncthreads();
#pragma unroll
    for (int ks = 0; ks < 4; ++ks) {
      const int sa = ((ks * 4 + lk + lrow) & 15) * 8;   // swizzled read slot
      short8 a[4], b[4];
#pragma unroll
      for (int mi = 0; mi < 4; ++mi)
        a[mi] = *(const short8*)&As[(wr * 64 + mi * 16 + lrow) * 128 + sa];
#pragma unroll
      for (int ni = 0; ni < 4; ++ni)
        b[ni] = *(const short8*)&Bs[(wc * 64 + ni * 16 + lrow) * 128 + sa];
#pragma unroll
      for (int mi = 0; mi < 4; ++mi)
#pragma unroll
        for (int ni = 0; ni < 4; ++ni)
          acc[mi][ni] = __builtin_amdgcn_mfma_f32_16x16x32_bf16(
              a[mi], b[ni], acc[mi][ni], 0, 0, 0);
    }
    __syncthreads();
  }

  float* Cf = (float*)Cv;
  hb* Cb = (hb*)Cv;
#pragma unroll
  for (int mi = 0; mi < 4; ++mi) {
#pragma unroll
    for (int ni = 0; ni < 4; ++ni) {
#pragma unroll
      for (int q = 0; q < 4; ++q) {
        int gm = bm + wr * 64 + mi * 16 + lk * 4 + q;
        int gn = bn + wc * 64 + ni * 16 + lrow;
        if (gm < M && gn < N) {
          float v = acc[mi][ni][q];
          if (bias) v += bias[gn];
          if (act)  v = gelu_f(v);
          long long off = cbase + (long long)gm * ldc + gn;
          if (out_mode == 1) Cb[off] = __float2bfloat16(v);
          else               Cf[off] = v;
        }
      }
    }
  }
}

// ---------------------------------------------------------------------------
// 8-phase deep-pipelined 256x256 GEMM (HK-style schedule in plain HIP).
// 512 threads = 8 waves (2M x 4N), per-wave 128x64 output, BK=64, dbuf LDS
// (128 KiB), counted vmcnt(4) once per K-tile, raw s_barrier, setprio(1)
// around each 16-MFMA quadrant.
//
// 3-term split-bf16 product expressed as K-segment concatenation:
//   seg0 = Ah.Bh, seg1 = Al.Bh, seg2 = Ah.Bl   (K' = nseg*K)
// nseg==1 -> plain bf16 GEMM (Al/Bl unused).
// Requires M%256==0, N%256==0, K%64==0.
// out_mode: 0 = f32, 1 = bf16, 2 = split hi/lo bf16.
//
// Issue schedule (per tile t, quadrant phases Q0,Q2,Q1,Q3):
//   ph1: read a(mi0-3)+b(ni0-1); issue B(t+1) half0
//   ph2: read a(mi4-7);          issue B(t+1) half1
//   ph3: read b(ni2-3);          issue A(t+2) half0   (A(t) consumed @ph2)
//   ph4: (no reads);             issue A(t+2) half1; vmcnt(4); barrier
// Safety: vmcnt precedes the trailing barrier so every wave's staged data
// is observed complete before any wave's next-tile ds_reads.
// ---------------------------------------------------------------------------
struct TS { const hb* a; const hb* b; int kk; };
__device__ __forceinline__ TS tsrc(int tt, int ntK,
    const hb* Ah, const hb* Al, const hb* Bh, const hb* Bl)
{
  int seg = (tt >= ntK) + (tt >= 2 * ntK);
  TS r;
  r.kk = (tt - seg * ntK) << 6;
  r.a = (seg == 1) ? Al : Ah;
  r.b = (seg == 2) ? Bl : Bh;
  return r;
}

#define STG(srcp, base, ldx, ldsp, h, kk) do {                               \
    const hb* _g = (srcp) + (base) + (long long)((h) * 128) * (ldx) + (kk);  \
    gload16(_g, (ldsp) + (h) * 8192 + tid * 8);                              \
    gload16(_g + 64LL * (ldx), (ldsp) + (h) * 8192 + 4096 + tid * 8);        \
  } while (0)

__global__ __launch_bounds__(512) void gemm8(
    const hb* __restrict__ Ah, const hb* __restrict__ Al,
    const hb* __restrict__ Bh, const hb* __restrict__ Bl,
    const float* __restrict__ bias, void* __restrict__ Cv,
    void* __restrict__ Cv2,
    int M, int N, int K, int lda, int ldb, int ldc,
    int act, int out_mode, int nseg)
{
  const int bm = blockIdx.y * 256, bn = blockIdx.x * 256;
  const int tid = threadIdx.x;
  const int lane = tid & 63;
  const int wv = tid >> 6, wr = wv >> 2, wc = wv & 3;
  const int lrow = lane & 15, lk = lane >> 4;
  const int ntK = K >> 6;
  const int NT = nseg * ntK;

  __shared__ __align__(16) hb As[2][256 * 64];
  __shared__ __align__(16) hb Bs[2][256 * 64];

  // staging map: row = tid>>3 (+64 per round, +128 per half), 8 slots of 16B
  const int srow = tid >> 3;
  const int sslot = ((tid & 7) - srow) & 7;   // inverse swizzle on global src
  const long long baseA = (long long)(bm + srow) * lda + sslot * 8;
  const long long baseB = (long long)(bn + srow) * ldb + sslot * 8;

  // fragment read map
  const int raBase = wr * 128 + lrow;
  const int rbBase = wc * 64 + lrow;
  const int psk0 = ((lk + lrow) & 7) * 8;       // swizzled slot, ks=0
  const int psk1 = ((4 + lk + lrow) & 7) * 8;   // ks=1

  f32x4 acc[8][4];
#pragma unroll
  for (int mi = 0; mi < 8; ++mi)
#pragma unroll
    for (int ni = 0; ni < 4; ++ni) acc[mi][ni] = (f32x4){0.f, 0.f, 0.f, 0.f};

  // ---- prologue: tile0 (A+B) -> buf0, tile1 (A only) -> buf1 ----
  {
    TS t0 = tsrc(0, ntK, Ah, Al, Bh, Bl);
    STG(t0.a, baseA, lda, &As[0][0], 0, t0.kk);
    STG(t0.a, baseA, lda, &As[0][0], 1, t0.kk);
    STG(t0.b, baseB, ldb, &Bs[0][0], 0, t0.kk);
    STG(t0.b, baseB, ldb, &Bs[0][0], 1, t0.kk);
    if (NT > 1) {
      TS t1 = tsrc(1, ntK, Ah, Al, Bh, Bl);
      STG(t1.a, baseA, lda, &As[1][0], 0, t1.kk);
      STG(t1.a, baseA, lda, &As[1][0], 1, t1.kk);
      asm volatile("s_waitcnt vmcnt(4)" ::: "memory");
    } else {
      asm volatile("s_waitcnt vmcnt(0)" ::: "memory");
    }
    __builtin_amdgcn_s_barrier();
  }

  short8 a0[4][2], a1[4][2], b0[2][2], b1[2][2];

  for (int t = 0; t < NT; ++t) {
    const int bf = t & 1;
    const hb* Ab = &As[bf][0];
    const hb* Bb = &Bs[bf][0];
    hb* AbW = &As[bf][0];          // A(t+2) lands in same buffer index
    hb* BbN = &Bs[bf ^ 1][0];      // B(t+1) lands in the other buffer
    const TS n1 = tsrc(t + 1, ntK, Ah, Al, Bh, Bl);
    const TS n2 = tsrc(t + 2, ntK, Ah, Al, Bh, Bl);
    const bool st1 = (t + 1 < NT), st2 = (t + 2 < NT);

    // ---- phase 1: Q0 = (mi 0-3) x (ni 0-1) ----
#pragma unroll
    for (int mi = 0; mi < 4; ++mi) {
      const int ra = (raBase + mi * 16) * 64;
      a0[mi][0] = *(const short8*)&Ab[ra + psk0];
      a0[mi][1] = *(const short8*)&Ab[ra + psk1];
    }
#pragma unroll
    for (int ni = 0; ni < 2; ++ni) {
      const int rb = (rbBase + ni * 16) * 64;
      b0[ni][0] = *(const short8*)&Bb[rb + psk0];
      b0[ni][1] = *(const short8*)&Bb[rb + psk1];
    }
    if (st1) STG(n1.b, baseB, ldb, BbN, 0, n1.kk);
    __builtin_amdgcn_s_barrier();
    asm volatile("s_waitcnt lgkmcnt(0)" ::: "memory");
    __builtin_amdgcn_sched_barrier(0);
    __builtin_amdgcn_s_setprio(1);
#pragma unroll
    for (int mi = 0; mi < 4; ++mi)
#pragma unroll
      for (int ni = 0; ni < 2; ++ni) {
        acc[mi][ni] = __builtin_amdgcn_mfma_f32_16x16x32_bf16(
            a0[mi][0], b0[ni][0], acc[mi][ni], 0, 0, 0);
        acc[mi][ni] = __builtin_amdgcn_mfma_f32_16x16x32_bf16(
            a0[mi][1], b0[ni][1], acc[mi][ni], 0, 0, 0);
      }
    __builtin_amdgcn_s_setprio(0);
    __builtin_amdgcn_s_barrier();

    // ---- phase 2: Q2 = (mi 4-7) x (ni 0-1) ----
#pragma unroll
    for (int mi = 0; mi < 4; ++mi) {
      const int ra = (raBase + (4 + mi) * 16) * 64;
      a1[mi][0] = *(const short8*)&Ab[ra + psk0];
      a1[mi][1] = *(const short8*)&Ab[ra + psk1];
    }
    if (st1) STG(n1.b, baseB, ldb, BbN, 1, n1.kk);
    __builtin_amdgcn_s_barrier();
    asm volatile("s_waitcnt lgkmcnt(0)" ::: "memory");
    __builtin_amdgcn_sched_barrier(0);
    __builtin_amdgcn_s_setprio(1);
#pragma unroll
    for (int mi = 0; mi < 4; ++mi)
#pragma unroll
      for (int ni = 0; ni < 2; ++ni) {
        acc[4 + mi][ni] = __builtin_amdgcn_mfma_f32_16x16x32_bf16(
            a1[mi][0], b0[ni][0], acc[4 + mi][ni], 0, 0, 0);
        acc[4 + mi][ni] = __builtin_amdgcn_mfma_f32_16x16x32_bf16(
            a1[mi][1], b0[ni][1], acc[4 + mi][ni], 0, 0, 0);
      }
    __builtin_amdgcn_s_setprio(0);
    __builtin_amdgcn_s_barrier();

    // ---- phase 3: Q1 = (mi 0-3) x (ni 2-3) ----
#pragma unroll
    for (int ni = 0; ni < 2; ++ni) {
      const int rb = (rbBase + (2 + ni) * 16) * 64;
      b1[ni][0] = *(const short8*)&Bb[rb + psk0];
      b1[ni][1] = *(const short8*)&Bb[rb + psk1];
    }
    if (st2) STG(n2.a, baseA, lda, AbW, 0, n2.kk);
    __builtin_amdgcn_s_barrier();
    asm volatile("s_waitcnt lgkmcnt(0)" ::: "memory");
    __builtin_amdgcn_sched_barrier(0);
    __builtin_amdgcn_s_setprio(1);
#pragma unroll
    for (int mi = 0; mi < 4; ++mi)
#pragma unroll
      for (int ni = 0; ni < 2; ++ni) {
        acc[mi][2 + ni] = __builtin_amdgcn_mfma_f32_16x16x32_bf16(
            a0[mi][0], b1[ni][0], acc[mi][2 + ni], 0, 0, 0);
        acc[mi][2 + ni] = __builtin_amdgcn_mfma_f32_16x16x32_bf16(
            a0[mi][1], b1[ni][1], acc[mi][2 + ni], 0, 0, 0);
      }
    __builtin_amdgcn_s_setprio(0);
    __builtin_amdgcn_s_barrier();

    // ---- phase 4: Q3 = (mi 4-7) x (ni 2-3) ----
    if (st2) STG(n2.a, baseA, lda, AbW, 1, n2.kk);
    __builtin_amdgcn_s_barrier();
    __builtin_amdgcn_s_setprio(1);
#pragma unroll
    for (int mi = 0; mi < 4; ++mi)
#pragma unroll
      for (int ni = 0; ni < 2; ++ni) {
        acc[4 + mi][2 + ni] = __builtin_amdgcn_mfma_f32_16x16x32_bf16(
            a1[mi][0], b1[ni][0], acc[4 + mi][2 + ni], 0, 0, 0);
        acc[4 + mi][2 + ni] = __builtin_amdgcn_mfma_f32_16x16x32_bf16(
            a1[mi][1], b1[ni][1], acc[4 + mi][2 + ni], 0, 0, 0);
      }
    __builtin_amdgcn_s_setprio(0);
    if (st2) asm volatile("s_waitcnt vmcnt(4)" ::: "memory");
    else     asm volatile("s_waitcnt vmcnt(0)" ::: "memory");
    __builtin_amdgcn_s_barrier();
  }

  float* Cf = (float*)Cv;
  hb* Cb = (hb*)Cv;
  hb* Cb2 = (hb*)Cv2;
#pragma unroll
  for (int mi = 0; mi < 8; ++mi) {
#pragma unroll
    for (int ni = 0; ni < 4; ++ni) {
#pragma unroll
      for (int q = 0; q < 4; ++q) {
        const int gm = bm + wr * 128 + mi * 16 + lk * 4 + q;
        const int gn = bn + wc * 64 + ni * 16 + lrow;
        float v = acc[mi][ni][q];
        if (bias) v += bias[gn];
        if (act)  v = gelu_f(v);
        const long long off = (long long)gm * ldc + gn;
        if (out_mode == 2) {
          unsigned short h = bf_bits(v);
          unsigned short l = bf_bits(v - bf_back(h));
          Cb[off] = *reinterpret_cast<hb*>(&h);
          Cb2[off] = *reinterpret_cast<hb*>(&l);
        } else if (out_mode == 1) {
          Cb[off] = __float2bfloat16(v);
        } else {
          Cf[off] = v;
        }
      }
    }
  }
}

// ---------------------------------------------------------------------------
// Banded MFMA: partial[kq][b][s][d] = proj[s].em[s+d] over K-quarter (3-term)
// ---------------------------------------------------------------------------
__global__ __launch_bounds__(256) void bandmm(
    const hb* __restrict__ Phi, const hb* __restrict__ Plo,
    const hb* __restrict__ Ehi, const hb* __restrict__ Elo,
    float* __restrict__ partial)
{
  const int s0 = blockIdx.x * 64;
  const int kq = blockIdx.y;
  const int b = blockIdx.z;
  const int tid = threadIdx.x;
  const int lane = tid & 63;
  const int wv = tid >> 6, wr = wv >> 1, wc = wv & 1;
  const int lrow = lane & 15, lk = lane >> 4;
  __shared__ __align__(16) hb As[64 * 64];
  __shared__ __align__(16) hb Bs[96 * 64];

  f32x4 acc[2][3];
#pragma unroll
  for (int mi = 0; mi < 2; ++mi)
#pragma unroll
    for (int ni = 0; ni < 3; ++ni) acc[mi][ni] = (f32x4){0.f, 0.f, 0.f, 0.f};

  const long long Pbase = (long long)(b * S_LEN) * FDIM;
  long long aoff[2], boff[3];
#pragma unroll
  for (int it = 0; it < 2; ++it) {
    int row = (tid + it * 256) >> 3;
    aoff[it] = Pbase + (long long)(s0 + row) * FDIM + (tid & 7) * 8;
  }
#pragma unroll
  for (int it = 0; it < 3; ++it) {
    int row = (tid + it * 256) >> 3;
    int t = s0 + row; if (t > S_LEN - 1) t = S_LEN - 1;
    boff[it] = Pbase + (long long)t * FDIM + (tid & 7) * 8;
  }

  const int kbeg = kq * (FDIM / 4), kend = kbeg + FDIM / 4;
  for (int t3 = 0; t3 < 3; ++t3) {
    const hb* Ap = (t3 == 1) ? Plo : Phi;
    const hb* Bp = (t3 == 2) ? Elo : Ehi;
    for (int k0 = kbeg; k0 < kend; k0 += 64) {
#pragma unroll
      for (int it = 0; it < 2; ++it)
        gload16(Ap + aoff[it] + k0, &As[(tid + it * 256) * 8]);
#pragma unroll
      for (int it = 0; it < 3; ++it)
        gload16(Bp + boff[it] + k0, &Bs[(tid + it * 256) * 8]);
      __syncthreads();
#pragma unroll
      for (int ks = 0; ks < 2; ++ks) {
        short8 a[2], bb[3];
#pragma unroll
        for (int mi = 0; mi < 2; ++mi)
          a[mi] = *(const short8*)&As[(wr * 32 + mi * 16 + lrow) * 64 + ks * 32 + lk * 8];
#pragma unroll
        for (int ni = 0; ni < 3; ++ni)
          bb[ni] = *(const short8*)&Bs[(wc * 48 + ni * 16 + lrow) * 64 + ks * 32 + lk * 8];
#pragma unroll
        for (int mi = 0; mi < 2; ++mi)
#pragma unroll
          for (int ni = 0; ni < 3; ++ni)
            acc[mi][ni] = __builtin_amdgcn_mfma_f32_16x16x32_bf16(
                a[mi], bb[ni], acc[mi][ni], 0, 0, 0);
      }
      __syncthreads();
    }
  }

#pragma unroll
  for (int mi = 0; mi < 2; ++mi) {
#pragma unroll
    for (int ni = 0; ni < 3; ++ni) {
#pragma unroll
      for (int q = 0; q < 4; ++q) {
        int i = wr * 32 + mi * 16 + lk * 4 + q;
        int n = wc * 48 + ni * 16 + lrow;
        int d = n - i;
        if (d >= 0 && d < 32) {
          long long off = (((long long)(kq * 2 + b)) * S_LEN + (s0 + i)) * 32 + d;
          partial[off] = acc[mi][ni][q];
        }
      }
    }
  }
}

// sum partials (fixed order), add ssc/esc, clip; -3e38 outside band
__global__ __launch_bounds__(256) void band_reduce(
    const float* __restrict__ partial, const float* __restrict__ ssc,
    const float* __restrict__ esc, float* __restrict__ band)
{
  int idx = blockIdx.x * 256 + threadIdx.x;
  if (idx >= BATCH * S_LEN * 32) return;
  int d = idx & 31;
  int s = (idx >> 5) & (S_LEN - 1);
  int b = idx >> 16;
  int t = s + d;
  float v;
  if (d < MAXSPAN && t < S_LEN) {
    float sum = 0.f;
#pragma unroll
    for (int kq = 0; kq < 4; ++kq)
      sum += partial[(((long long)(kq * 2 + b)) * S_LEN + s) * 32 + d];
    sum += ssc[b * S_LEN + s] + esc[b * S_LEN + t];
    v = fminf(fmaxf(sum, NEGV), -NEGV);
  } else {
    v = -3.0e38f;
  }
  band[idx] = v;
}

// ---------------------------------------------------------------------------
__global__ __launch_bounds__(256) void split_mat(
    const float* __restrict__ src, hb* __restrict__ hi, hb* __restrict__ lo,
    long long n4)
{
  long long i = (long long)blockIdx.x * 256 + threadIdx.x;
  if (i >= n4) return;
  float4 v = ((const float4*)src)[i];
  unsigned short h[4], l[4];
  float vv[4] = {v.x, v.y, v.z, v.w};
#pragma unroll
  for (int j = 0; j < 4; ++j) {
    h[j] = bf_bits(vv[j]);
    l[j] = bf_bits(vv[j] - bf_back(h[j]));
  }
  ((uint2*)hi)[i] = *(uint2*)h;
  ((uint2*)lo)[i] = *(uint2*)l;
}

// split + transpose: src f32 [K][N] -> hiT,loT bf16 [N][K]
__global__ __launch_bounds__(256) void splitT_mat(
    const float* __restrict__ src, hb* __restrict__ hiT, hb* __restrict__ loT,
    int K, int N)
{
  __shared__ float t[32][33];
  int k0 = blockIdx.y * 32, n0 = blockIdx.x * 32;
  int tx = threadIdx.x & 31, ty = threadIdx.x >> 5;
#pragma unroll
  for (int r = 0; r < 4; ++r)
    t[ty + r * 8][tx] = src[(long long)(k0 + ty + r * 8) * N + (n0 + tx)];
  __syncthreads();
#pragma unroll
  for (int r = 0; r < 4; ++r) {
    int n = n0 + ty + r * 8;
    float v = t[tx][ty + r * 8];
    unsigned short h = bf_bits(v);
    unsigned short l = bf_bits(v - bf_back(h));
    hiT[(long long)n * K + k0 + tx] = *reinterpret_cast<hb*>(&h);
    loT[(long long)n * K + k0 + tx] = *reinterpret_cast<hb*>(&l);
  }
}

// ---------------------------------------------------------------------------
// Fused LayerNorm (fp64 stats) + hi/lo bf16 split + cls row-dot (fp64 accum)
// ---------------------------------------------------------------------------
__global__ __launch_bounds__(256) void ln_split_dot(
    const float* __restrict__ src, hb* __restrict__ hi, hb* __restrict__ lo,
    const float* __restrict__ g, const float* __restrict__ be,
    const float* __restrict__ w, const float* __restrict__ wb,
    float* __restrict__ dot_out)
{
  __shared__ float row[FDIM];
  __shared__ double scr[4];
  __shared__ double sh_mu, sh_rstd;
  const long long r = blockIdx.x;
  const float* p = src + r * FDIM;
  const int tid = threadIdx.x;

  double s = 0.0;
#pragma unroll
  for (int pp = 0; pp < 3; ++pp) {
    int c4 = pp * 256 + tid;
    float4 v = *(const float4*)(p + c4 * 4);
    *(float4*)&row[c4 * 4] = v;
    s += (double)v.x + (double)v.y + (double)v.z + (double)v.w;
  }
#pragma unroll
  for (int off = 32; off; off >>= 1) s += __shfl_down(s, off, 64);
  if ((tid & 63) == 0) scr[tid >> 6] = s;
  __syncthreads();
  if (tid == 0) sh_mu = (scr[0] + scr[1] + scr[2] + scr[3]) / FDIM;
  __syncthreads();
  double mu = sh_mu;
  double vs = 0.0;
#pragma unroll
  for (int pp = 0; pp < 12; ++pp) {
    double d = (double)row[pp * 256 + tid] - mu;
    vs += d * d;
  }
#pragma unroll
  for (int off = 32; off; off >>= 1) vs += __shfl_down(vs, off, 64);
  __syncthreads();
  if ((tid & 63) == 0) scr[tid >> 6] = vs;
  __syncthreads();
  if (tid == 0)
    sh_rstd = 1.0 / sqrt((scr[0] + scr[1] + scr[2] + scr[3]) / FDIM + 1e-5);
  __syncthreads();
  double rstd = sh_rstd;

  double dot = 0.0;
#pragma unroll
  for (int pp = 0; pp < 3; ++pp) {
    int c4 = pp * 256 + tid;
    float4 gv = *(const float4*)(g + c4 * 4);
    float4 bv = *(const float4*)(be + c4 * 4);
    float4 wv = *(const float4*)(w + c4 * 4);
    float xv[4];
    *(float4*)xv = *(const float4*)&row[c4 * 4];
    unsigned short hh[4], ll[4];
    float gg[4] = {gv.x, gv.y, gv.z, gv.w};
    float bb[4] = {bv.x, bv.y, bv.z, bv.w};
    float ww[4] = {wv.x, wv.y, wv.z, wv.w};
#pragma unroll
    for (int j = 0; j < 4; ++j) {
      float val = (float)(((double)xv[j] - mu) * rstd * (double)gg[j] + (double)bb[j]);
      dot += (double)val * (double)ww[j];
      hh[j] = bf_bits(val);
      ll[j] = bf_bits(val - bf_back(hh[j]));
    }
    *(uint2*)(hi + r * FDIM + c4 * 4) = *(uint2*)hh;
    *(uint2*)(lo + r * FDIM + c4 * 4) = *(uint2*)ll;
  }
#pragma unroll
  for (int off = 32; off; off >>= 1) dot += __shfl_down(dot, off, 64);
  __syncthreads();
  if ((tid & 63) == 0) scr[tid >> 6] = dot;
  __syncthreads();
  if (tid == 0)
    dot_out[r] = (float)(scr[0] + scr[1] + scr[2] + scr[3] + (double)wb[0]);
}

// LayerNorm f32 src -> bf16 dst (phase-2)
__global__ __launch_bounds__(256) void ln_rows_bf(
    const float* __restrict__ src, hb* __restrict__ dst,
    const float* __restrict__ g, const float* __restrict__ be,
    int n, long long lds_, long long ldd)
{
  long long r = blockIdx.x;
  const float* p = src + r * lds_;
  hb* d = dst + r * ldd;
  __shared__ double scratch[4];
  __shared__ double sh_mu, sh_rstd;
  double s = 0.0;
  for (int c = threadIdx.x; c < n; c += 256) s += (double)p[c];
#pragma unroll
  for (int off = 32; off; off >>= 1) s += __shfl_down(s, off, 64);
  if ((threadIdx.x & 63) == 0) scratch[threadIdx.x >> 6] = s;
  __syncthreads();
  if (threadIdx.x == 0) sh_mu = (scratch[0] + scratch[1] + scratch[2] + scratch[3]) / n;
  __syncthreads();
  double mu = sh_mu;
  double vs = 0.0;
  for (int c = threadIdx.x; c < n; c += 256) { double dd = (double)p[c] - mu; vs += dd * dd; }
#pragma unroll
  for (int off = 32; off; off >>= 1) vs += __shfl_down(vs, off, 64);
  __syncthreads();
  if ((threadIdx.x & 63) == 0) scratch[threadIdx.x >> 6] = vs;
  __syncthreads();
  if (threadIdx.x == 0)
    sh_rstd = 1.0 / sqrt((scratch[0] + scratch[1] + scratch[2] + scratch[3]) / n + 1e-5);
  __syncthreads();
  double rstd = sh_rstd;
  for (int c = threadIdx.x; c < n; c += 256)
    d[c] = __float2bfloat16(
        (float)(((double)p[c] - mu) * rstd * (double)g[c] + (double)be[c]));
}

// ---------------------------------------------------------------------------
// Top-k selection (radix on monotone float keys) + index sort, 1 block/batch
// ---------------------------------------------------------------------------
__device__ __forceinline__ unsigned f2k(float f) {
  unsigned u = __float_as_uint(f);
  return (u & 0x80000000u) ? ~u : (u | 0x80000000u);
}

__device__ void bitonic1024(int* a) {
  const int tid = threadIdx.x;
  for (int sz = 2; sz <= 1024; sz <<= 1) {
    for (int st = sz >> 1; st > 0; st >>= 1) {
      __syncthreads();
      int j = tid ^ st;
      if (j > tid) {
        int x = a[tid], y = a[j];
        bool asc = (tid & sz) == 0;
        if ((x > y) == asc) { a[tid] = y; a[j] = x; }
      }
    }
  }
  __syncthreads();
}

__global__ __launch_bounds__(1024) void select_sort(
    const float* __restrict__ band, const int* __restrict__ masks,
    int* __restrict__ sidx, int* __restrict__ starts, int* __restrict__ ends,
    float* __restrict__ tms, int* __restrict__ kvals)
{
  const int b = blockIdx.x;
  const int tid = threadIdx.x;
  __shared__ int hist[256];
  __shared__ int sel[1024];
  __shared__ int eq[1024];
  __shared__ int sred[16];
  __shared__ int cvar[4];
  __shared__ int cnt_gt, cnt_eq;

  int msum = 0;
  for (int i = tid; i < S_LEN; i += 1024) msum += masks[b * S_LEN + i];
#pragma unroll
  for (int off = 32; off; off >>= 1) msum += __shfl_down(msum, off, 64);
  if ((tid & 63) == 0) sred[tid >> 6] = msum;
  __syncthreads();
  if (tid == 0) {
    int t = 0;
    for (int w = 0; w < 16; ++w) t += sred[w];
    cvar[2] = t;
  }
  __syncthreads();
  int kv = (int)((float)cvar[2] * 0.4f);
  if (kv > MAXK) kv = MAXK;
  if (kv < 0) kv = 0;

  const int NC = S_LEN * MAXSPAN;
  unsigned prefix = 0u;
  int remaining = kv;

  if (kv > 0) {
    for (int byte = 3; byte >= 0; --byte) {
      if (tid < 256) hist[tid] = 0;
      __syncthreads();
      for (int i = tid; i < NC; i += 1024) {
        int s = i / MAXSPAN;
        int d = i - s * MAXSPAN;
        float v = band[((long long)(b * S_LEN + s)) * 32 + d];
        unsigned key = f2k(v);
        bool match = (byte == 3) ||
            ((key >> ((byte + 1) * 8)) == (prefix >> ((byte + 1) * 8)));
        if (match) atomicAdd(&hist[(key >> (byte * 8)) & 255], 1);
      }
      __syncthreads();
      if (tid == 0) {
        int cum = 0, chosen = 255;
        for (int v = 255; v >= 0; --v) {
          int h = hist[v];
          if (cum + h >= remaining) { chosen = v; cvar[0] = remaining - cum; break; }
          cum += h;
        }
        cvar[1] = chosen;
      }
      __syncthreads();
      remaining = cvar[0];
      prefix |= ((unsigned)cvar[1]) << (byte * 8);
      __syncthreads();
    }
    if (tid == 0) { cnt_gt = 0; cnt_eq = 0; }
    __syncthreads();
    for (int i = tid; i < NC; i += 1024) {
      int s = i / MAXSPAN;
      int d = i - s * MAXSPAN;
      float v = band[((long long)(b * S_LEN + s)) * 32 + d];
      unsigned key = f2k(v);
      int flat = s * S_LEN + s + d;
      if (key > prefix) {
        int p = atomicAdd(&cnt_gt, 1);
        if (p < MAXK) sel[p] = flat;
      } else if (key == prefix) {
        int p = atomicAdd(&cnt_eq, 1);
        if (p < 1024) eq[p] = flat;
      }
    }
    __syncthreads();
    int ngt = cnt_gt;
    int neq = cnt_eq; if (neq > 1024) neq = 1024;
    if (tid >= neq) eq[tid] = 0x7FFFFFFF;
    __syncthreads();
    bitonic1024(eq);
    int need = kv - ngt;
    if (tid < need) sel[ngt + tid] = eq[tid];
    __syncthreads();
  }
  if (tid >= kv && tid < MAXK) sel[tid] = S_LEN * S_LEN - 1;
  if (tid >= MAXK) sel[tid] = 0x7FFFFFFF;
  __syncthreads();
  bitonic1024(sel);
  if (tid < MAXK) {
    int idx = sel[tid];
    int s = idx >> 11;
    int t = idx & (S_LEN - 1);
    sidx[b * MAXK + tid] = idx;
    starts[b * MAXK + tid] = s;
    ends[b * MAXK + tid] = t;
    tms[b * MAXK + tid] = band[((long long)(b * S_LEN + s)) * 32 + (t - s)];
  }
  if (tid == 0) kvals[b] = kv;
}

// dst[b*MAXK+j, :] = bf16(src[b, rows[b*MAXK+j], :])   (H = 1024)
__global__ __launch_bounds__(256) void gather_bf(
    const float* __restrict__ src, const int* __restrict__ rows,
    hb* __restrict__ dst)
{
  int g = blockIdx.x;
  int b = g / MAXK;
  int r = rows[g];
  const float4* s4 = (const float4*)(src + ((long long)(b * S_LEN + r)) * HDIM);
  hb* d = dst + (long long)g * HDIM;
  float4 v = s4[threadIdx.x];
  d[threadIdx.x * 4 + 0] = __float2bfloat16(v.x);
  d[threadIdx.x * 4 + 1] = __float2bfloat16(v.y);
  d[threadIdx.x * 4 + 2] = __float2bfloat16(v.z);
  d[threadIdx.x * 4 + 3] = __float2bfloat16(v.w);
}

// transpose+convert: dst[n][koff + k] (bf16, row stride ldd) = src[k][n] (f32)
__global__ __launch_bounds__(256) void conv_t(
    const float* __restrict__ src, hb* __restrict__ dst,
    int K, int N, int koff, int ldd)
{
  __shared__ float t[32][33];
  int k0 = blockIdx.y * 32, n0 = blockIdx.x * 32;
  int tx = threadIdx.x & 31, ty = threadIdx.x >> 5;
#pragma unroll
  for (int r = 0; r < 4; ++r)
    t[ty + r * 8][tx] = src[(long long)(k0 + ty + r * 8) * N + (n0 + tx)];
  __syncthreads();
#pragma unroll
  for (int r = 0; r < 4; ++r) {
    int n = n0 + ty + r * 8;
    dst[(long long)n * ldd + koff + k0 + tx] = __float2bfloat16(t[tx][ty + r * 8]);
  }
}

__global__ __launch_bounds__(256) void add2(
    const float* __restrict__ a, const float* __restrict__ b,
    float* __restrict__ c, int n)
{
  int i = blockIdx.x * 256 + threadIdx.x;
  if (i < n) c[i] = a[i] + b[i];
}

// out[b,i,j] assembly: sum 4 coref K-slices + pair + anaphora mask, zero last col
__global__ __launch_bounds__(256) void final_assemble(
    const float* __restrict__ coref4, const float* __restrict__ tms,
    const int* __restrict__ kvals, float* __restrict__ out)
{
  const long long SL = (long long)MAXK * MAXK;   // slice stride
  int g = blockIdx.x;                   // b*MAXK + i
  int b = g / MAXK;
  int i = g - b * MAXK;
  int kv = kvals[b];
  float ti = tms[g];
  const float* crow = coref4 + (long long)(b * 4) * SL + (long long)i * MAXK;
  float* orow = out + (long long)b * MAXK * (MAXK + 1) + (long long)i * (MAXK + 1);
  for (int j = threadIdx.x; j < MAXK + 1; j += 256) {
    float v;
    if (j == MAXK) v = 0.f;
    else {
      float c = ((crow[j] + crow[j + SL]) + (crow[j + 2 * SL] + crow[j + 3 * SL]));
      v = ti + tms[b * MAXK + j] + c;
      if (!((j < i) && (i < kv))) v += NEGV;
      v = fminf(fmaxf(v, NEGV), -NEGV);
    }
    orow[j] = v;
  }
}

// ---------------------------------------------------------------------------
static inline void launch1(const hb* A, const hb* B, const float* bias, void* C,
    int M, int N, int K, int lda, int ldb, int ldc,
    long long sA, long long sB, long long sC,
    int act, int out_mode, int zcount, int kspl, hipStream_t stream)
{
  dim3 grid((N + 127) / 128, (M + 127) / 128, zcount);
  gemm_fast1<<<grid, 256, 0, stream>>>(A, B, bias, C, M, N, K, lda, ldb, ldc,
                                       sA, sB, sC, act, out_mode, kspl);
}

static inline void launch8(const hb* Ah, const hb* Al, const hb* Bh, const hb* Bl,
    const float* bias, void* C, void* C2, int M, int N, int K,
    int lda, int ldb, int ldc, int act, int out_mode, int nseg, hipStream_t stream)
{
  dim3 grid(N / 256, M / 256, 1);
  gemm8<<<grid, 512, 0, stream>>>(Ah, Al, Bh, Bl, bias, C, C2,
                                  M, N, K, lda, ldb, ldc, act, out_mode, nseg);
}

extern "C" void kernel_launch(void* const* d_in, const int* in_sizes, int n_in,
                              void* d_out, int out_size, void* d_ws, size_t ws_size,
                              hipStream_t stream) {
  const float* input_emb = (const float*)d_in[0];
  const int*   input_masks = (const int*)d_in[1];
  const float* sm_W = (const float*)d_in[2];
  const float* sm_b = (const float*)d_in[3];
  const float* sm_g = (const float*)d_in[4];
  const float* sm_be = (const float*)d_in[5];
  const float* em_W = (const float*)d_in[6];
  const float* em_b = (const float*)d_in[7];
  const float* em_g = (const float*)d_in[8];
  const float* em_be = (const float*)d_in[9];
  const float* sc_W = (const float*)d_in[10];
  const float* sc_b = (const float*)d_in[11];
  const float* sc_g = (const float*)d_in[12];
  const float* sc_be = (const float*)d_in[13];
  const float* ec_W = (const float*)d_in[14];
  const float* ec_b = (const float*)d_in[15];
  const float* ec_g = (const float*)d_in[16];
  const float* ec_be = (const float*)d_in[17];
  const float* cls_s_W = (const float*)d_in[18];
  const float* cls_s_b = (const float*)d_in[19];
  const float* cls_e_W = (const float*)d_in[20];
  const float* cls_e_b = (const float*)d_in[21];
  const float* s2e_W = (const float*)d_in[22];
  const float* s2e_b = (const float*)d_in[23];
  const float* a_ss_W = (const float*)d_in[24];
  const float* a_ss_b = (const float*)d_in[25];
  const float* a_ee_W = (const float*)d_in[26];
  const float* a_ee_b = (const float*)d_in[27];
  const float* a_se_W = (const float*)d_in[28];
  const float* a_se_b = (const float*)d_in[29];
  const float* a_es_W = (const float*)d_in[30];
  const float* a_es_b = (const float*)d_in[31];
  float* out = (float*)d_out;

  const int NROW = BATCH * S_LEN;           // 4096
  const int MROW = BATCH * MAXK;            // 1638
  const long long SZ_BIG = (long long)NROW * FDIM * 4;      // 50331648

  char* ws = (char*)d_ws;
  // ---- phase-1 regions (schedule in launch order) ----
  float* smF    = (float*)(ws);                     // sm f32, dead after LN
  hb* sm_hi     = (hb*)(ws + 50331648LL);
  hb* sm_lo     = (hb*)(ws + 75497472LL);
  hb* emb_hi    = (hb*)(ws + 100663296LL);
  hb* emb_lo    = (hb*)(ws + 109051904LL);
  hb* w1_hiT    = (hb*)(ws + 117440512LL);
  hb* w1_loT    = (hb*)(ws + 123731968LL);
  hb* s2e_hiT   = (hb*)(ws);                        // after smF dead
  hb* s2e_loT   = (hb*)(ws + 18874368LL);
  hb* proj_hi   = (hb*)(ws + 100663296LL);          // after emb/w1 dead
  hb* proj_lo   = (hb*)(ws + 125829120LL);
  hb* emb2_hi   = (hb*)(ws);                        // after s2eT dead
  hb* emb2_lo   = (hb*)(ws + 8388608LL);
  hb* w2_hiT    = (hb*)(ws + 16777216LL);
  hb* w2_loT    = (hb*)(ws + 23068672LL);
  float* emF    = (float*)(ws + 50331648LL);        // after sm splits dead
  hb* em_hi     = (hb*)(ws);                        // after emb2/w2 dead
  hb* em_lo     = (hb*)(ws + 25165824LL);
  float* partial = (float*)(ws + 50331648LL);       // after emF dead, 2 MB
  // ---- phase-2 overlay ----
  hb* tkcat = (hb*)(ws);                            // [1638][6144]
  hb* qcat  = (hb*)(ws + 20127744LL);
  float* mlp_s = (float*)(ws + 40255488LL);
  float* mlp_e = (float*)(ws + 60383232LL);
  hb* Xs_bf = (hb*)(ws + 80510976LL);
  hb* Xe_bf = (hb*)(ws + 83865600LL);
  hb* scWt  = (hb*)(ws + 87220224LL);
  hb* ecWt  = (hb*)(ws + 93511680LL);
  float* coref4 = (float*)(ws + 99803136LL);        // [2][4][819][819] f32, 21.5 MB
  hb* Wq1t = (hb*)(ws + 40255488LL);                // [3072][6144]
  hb* Wq2t = (hb*)(ws + 78004224LL);                // contiguous after Wq1t
  // ---- persistent tail ----
  const long long P = 3 * SZ_BIG;                   // 150994944
  float* band = (float*)(ws + P);
  float* ssc  = (float*)(ws + P + 524288);
  float* esc  = (float*)(ws + P + 540672);
  int* sidx   = (int*)(ws + P + 557056);
  int* starts = (int*)(ws + P + 565248);
  int* ends   = (int*)(ws + P + 573440);
  float* tms  = (float*)(ws + P + 581632);
  int* kvals  = (int*)(ws + P + 589824);
  float* biasq1 = (float*)(ws + P + 590080);        // [3072]
  float* biasq2 = (float*)(ws + P + 602368);        // contiguous -> [6144] cat
  if (ws_size < (size_t)(P + 614656)) return;

  const long long n4_emb = (long long)NROW * HDIM / 4;

  // ---- phase 1: selection-critical chain ----
  split_mat<<<(int)((n4_emb + 255) / 256), 256, 0, stream>>>(input_emb, emb_hi, emb_lo, n4_emb);
  splitT_mat<<<dim3(FDIM / 32, HDIM / 32), 256, 0, stream>>>(sm_W, w1_hiT, w1_loT, HDIM, FDIM);
  launch8(emb_hi, emb_lo, w1_hiT, w1_loT, sm_b, smF, nullptr,
          NROW, FDIM, HDIM, HDIM, HDIM, FDIM, 1, 0, 3, stream);
  ln_split_dot<<<NROW, 256, 0, stream>>>(smF, sm_hi, sm_lo, sm_g, sm_be,
                                         cls_s_W, cls_s_b, ssc);
  splitT_mat<<<dim3(FDIM / 32, FDIM / 32), 256, 0, stream>>>(s2e_W, s2e_hiT, s2e_loT, FDIM, FDIM);
  launch8(sm_hi, sm_lo, s2e_hiT, s2e_loT, s2e_b, proj_hi, proj_lo,
          NROW, FDIM, FDIM, FDIM, FDIM, FDIM, 0, 2, 3, stream);
  split_mat<<<(int)((n4_emb + 255) / 256), 256, 0, stream>>>(input_emb, emb2_hi, emb2_lo, n4_emb);
  splitT_mat<<<dim3(FDIM / 32, HDIM / 32), 256, 0, stream>>>(em_W, w2_hiT, w2_loT, HDIM, FDIM);
  launch8(emb2_hi, emb2_lo, w2_hiT, w2_loT, em_b, emF, nullptr,
          NROW, FDIM, HDIM, HDIM, HDIM, FDIM, 1, 0, 3, stream);
  ln_split_dot<<<NROW, 256, 0, stream>>>(emF, em_hi, em_lo, em_g, em_be,
                                         cls_e_W, cls_e_b, esc);
  bandmm<<<dim3(S_LEN / 64, 4, BATCH), 256, 0, stream>>>(proj_hi, proj_lo, em_hi, em_lo, partial);
  band_reduce<<<(BATCH * S_LEN * 32) / 256, 256, 0, stream>>>(partial, ssc, esc, band);
  select_sort<<<BATCH, 1024, 0, stream>>>(band, input_masks, sidx, starts, ends, tms, kvals);

  // ---- phase 2: gathered coref reps, bf16 MFMA ----
  gather_bf<<<MROW, 256, 0, stream>>>(input_emb, starts, Xs_bf);
  gather_bf<<<MROW, 256, 0, stream>>>(input_emb, ends, Xe_bf);

  conv_t<<<dim3(FDIM / 32, HDIM / 32), 256, 0, stream>>>(sc_W, scWt, HDIM, FDIM, 0, HDIM);
  conv_t<<<dim3(FDIM / 32, HDIM / 32), 256, 0, stream>>>(ec_W, ecWt, HDIM, FDIM, 0, HDIM);

  launch1(Xs_bf, scWt, sc_b, mlp_s, MROW, FDIM, HDIM, HDIM, HDIM, FDIM,
          0, 0, 0, 1, 0, 1, 1, stream);
  launch1(Xe_bf, ecWt, ec_b, mlp_e, MROW, FDIM, HDIM, HDIM, HDIM, FDIM,
          0, 0, 0, 1, 0, 1, 1, stream);

  ln_rows_bf<<<MROW, 256, 0, stream>>>(mlp_s, tkcat, sc_g, sc_be, FDIM, FDIM, 2 * FDIM);
  ln_rows_bf<<<MROW, 256, 0, stream>>>(mlp_e, tkcat + FDIM, ec_g, ec_be, FDIM, FDIM, 2 * FDIM);

  conv_t<<<dim3(FDIM / 32, FDIM / 32), 256, 0, stream>>>(a_ss_W, Wq1t, FDIM, FDIM, 0,    2 * FDIM);
  conv_t<<<dim3(FDIM / 32, FDIM / 32), 256, 0, stream>>>(a_es_W, Wq1t, FDIM, FDIM, FDIM, 2 * FDIM);
  conv_t<<<dim3(FDIM / 32, FDIM / 32), 256, 0, stream>>>(a_se_W, Wq2t, FDIM, FDIM, 0,    2 * FDIM);
  conv_t<<<dim3(FDIM / 32, FDIM / 32), 256, 0, stream>>>(a_ee_W, Wq2t, FDIM, FDIM, FDIM, 2 * FDIM);
  add2<<<FDIM / 256, 256, 0, stream>>>(a_ss_b, a_es_b, biasq1, FDIM);
  add2<<<FDIM / 256, 256, 0, stream>>>(a_se_b, a_ee_b, biasq2, FDIM);

  // fused qcat: N = 6144 over contiguous [Wq1t; Wq2t] and [biasq1|biasq2]
  launch1(tkcat, Wq1t, biasq1, qcat, MROW, 2 * FDIM, 2 * FDIM,
          2 * FDIM, 2 * FDIM, 2 * FDIM, 0, 0, 0, 0, 1, 1, 1, stream);

  // coref: split-K x4 (K=1536/slice), batched z = b*4 + ks
  launch1(qcat, tkcat, nullptr, coref4, MAXK, MAXK, 1536,
          2 * FDIM, 2 * FDIM, MAXK,
          (long long)MAXK * 2 * FDIM, (long long)MAXK * 2 * FDIM,
          (long long)MAXK * MAXK, 0, 0, BATCH * 4, 4, stream);

  final_assemble<<<MROW, 256, 0, stream>>>(coref4, tms, kvals, out);
}

// Round 2
// 1283.555 us; speedup vs baseline: 1.0964x; 1.0964x over previous
//
#include <hip/hip_runtime.h>
#include <hip/hip_bf16.h>
#include <math.h>

#define S_LEN 2048
#define BATCH 2
#define HDIM 1024
#define FDIM 3072
#define MAXK 819
#define MAXSPAN 30
#define NEGV -10000.0f

typedef __attribute__((ext_vector_type(8))) short short8;
typedef __attribute__((ext_vector_type(4))) float f32x4;
typedef __hip_bfloat16 hb;

__device__ __forceinline__ float gelu_f(float x) {
  return 0.5f * x * (1.0f + erff(x * 0.70710678118654752440f));
}

__device__ __forceinline__ unsigned short bf_bits(float x) {
  hb b = __float2bfloat16(x);
  return *reinterpret_cast<unsigned short*>(&b);
}
__device__ __forceinline__ float bf_back(unsigned short u) {
  hb b = *reinterpret_cast<hb*>(&u);
  return __bfloat162float(b);
}

__device__ __forceinline__ void gload16(const void* g, void* l) {
  __builtin_amdgcn_global_load_lds(
      (const __attribute__((address_space(1))) void*)g,
      (__attribute__((address_space(3))) void*)l, 16, 0, 0);
}

// Bijective XCD-chunked block remap (m204): blocks the HW round-robins to the
// same XCD (orig%8) get a contiguous chunk of logical tile ids -> same-row
// tiles share operand panels in that XCD's private L2. Bijective for any nwg.
struct B3 { int x, y, z; };
__device__ __forceinline__ B3 xcd_remap() {
  const int gx = gridDim.x, gy = gridDim.y;
  const int nwg = gx * gy * gridDim.z;
  const int orig = (blockIdx.z * gy + blockIdx.y) * gx + blockIdx.x;
  const int q = nwg >> 3, r = nwg & 7;
  const int xc = orig & 7, o = orig >> 3;
  const int wg = (xc < r ? xc * (q + 1) : r * (q + 1) + (xc - r) * q) + o;
  B3 b; b.x = wg % gx; b.y = (wg / gx) % gy; b.z = wg / (gx * gy);
  return b;
}

// ---------------------------------------------------------------------------
// bf16 MFMA GEMM, single-term, BK=128 (128 MFMA per barrier-pair).
// C[M,N] = act(A[M,K] @ B[N,K]^T + bias).  K multiple of 128.
// kspl>1: split-K — z-slice zk covers k in [zk*K, (zk+1)*K); C slice at
// z * sC (sum slices downstream).
// Swizzled LDS slots (16 x 16B per row), linear gload_lds dest.
// out_mode: 0 = f32, 1 = bf16.
// ---------------------------------------------------------------------------
__global__ __launch_bounds__(256) void gemm_fast1(
    const hb* __restrict__ A, const hb* __restrict__ B,
    const float* __restrict__ bias, void* __restrict__ Cv,
    int M, int N, int K, int lda, int ldb, int ldc,
    long long sA, long long sB, long long sC,
    int act, int out_mode, int kspl)
{
  const B3 bid = xcd_remap();
  const int zb = bid.z / kspl, zk = bid.z - zb * kspl;
  A += (long long)zb * sA + (long long)zk * K;
  B += (long long)zb * sB + (long long)zk * K;
  const long long cbase = (long long)bid.z * sC;
  const int bm = bid.y * 128, bn = bid.x * 128;
  const int tid = threadIdx.x;
  const int lane = tid & 63;
  const int wv = tid >> 6, wr = wv >> 1, wc = wv & 1;
  const int lrow = lane & 15, lk = lane >> 4;
  __shared__ __align__(16) hb As[128 * 128];
  __shared__ __align__(16) hb Bs[128 * 128];

  const int srow = tid >> 4;          // 0..15
  const int sc8 = tid & 15;           // 16 slots of 8 bf16
  const int sslot = (sc8 - srow) & 15;  // inverse swizzle on global source

  f32x4 acc[4][4];
#pragma unroll
  for (int mi = 0; mi < 4; ++mi)
#pragma unroll
    for (int ni = 0; ni < 4; ++ni) acc[mi][ni] = (f32x4){0.f, 0.f, 0.f, 0.f};

  long long aoff[8], boff[8];
#pragma unroll
  for (int it = 0; it < 8; ++it) {
    int gm = bm + srow + it * 16; if (gm > M - 1) gm = M - 1;
    int gn = bn + srow + it * 16; if (gn > N - 1) gn = N - 1;
    aoff[it] = (long long)gm * lda + sslot * 8;
    boff[it] = (long long)gn * ldb + sslot * 8;
  }

  for (int k0 = 0; k0 < K; k0 += 128) {
#pragma unroll
    for (int it = 0; it < 8; ++it)
      gload16(A + aoff[it] + k0, &As[(tid + it * 256) * 8]);
#pragma unroll
    for (int it = 0; it < 8; ++it)
      gload16(B + boff[it] + k0, &Bs[(tid + it * 256) * 8]);
    __syncthreads();
#pragma unroll
    for (int ks = 0; ks < 4; ++ks) {
      const int sa = ((ks * 4 + lk + lrow) & 15) * 8;   // swizzled read slot
      short8 a[4], b[4];
#pragma unroll
      for (int mi = 0; mi < 4; ++mi)
        a[mi] = *(const short8*)&As[(wr * 64 + mi * 16 + lrow) * 128 + sa];
#pragma unroll
      for (int ni = 0; ni < 4; ++ni)
        b[ni] = *(const short8*)&Bs[(wc * 64 + ni * 16 + lrow) * 128 + sa];
#pragma unroll
      for (int mi = 0; mi < 4; ++mi)
#pragma unroll
        for (int ni = 0; ni < 4; ++ni)
          acc[mi][ni] = __builtin_amdgcn_mfma_f32_16x16x32_bf16(
              a[mi], b[ni], acc[mi][ni], 0, 0, 0);
    }
    __syncthreads();
  }

  float* Cf = (float*)Cv;
  hb* Cb = (hb*)Cv;
#pragma unroll
  for (int mi = 0; mi < 4; ++mi) {
#pragma unroll
    for (int ni = 0; ni < 4; ++ni) {
#pragma unroll
      for (int q = 0; q < 4; ++q) {
        int gm = bm + wr * 64 + mi * 16 + lk * 4 + q;
        int gn = bn + wc * 64 + ni * 16 + lrow;
        if (gm < M && gn < N) {
          float v = acc[mi][ni][q];
          if (bias) v += bias[gn];
          if (act)  v = gelu_f(v);
          long long off = cbase + (long long)gm * ldc + gn;
          if (out_mode == 1) Cb[off] = __float2bfloat16(v);
          else               Cf[off] = v;
        }
      }
    }
  }
}

// ---------------------------------------------------------------------------
// Fused split-bf16 3-term GEMM (fp32-equivalent): stages A_hi,A_lo,B_hi,B_lo
// once per K-tile (64KB LDS), 96 MFMAs per K-tile (hh + lh + hl). BK=64.
// out_mode: 0 = f32, 2 = split hi/lo bf16.
// ---------------------------------------------------------------------------
__global__ __launch_bounds__(256) void gemm_fast3(
    const hb* __restrict__ Ah, const hb* __restrict__ Al,
    const hb* __restrict__ Bh, const hb* __restrict__ Bl,
    const float* __restrict__ bias, void* __restrict__ Cv, void* __restrict__ Cv2,
    int M, int N, int K, int lda, int ldb, int ldc, int act, int out_mode)
{
  const B3 bid = xcd_remap();
  const int bm = bid.y * 128, bn = bid.x * 128;
  const int tid = threadIdx.x;
  const int lane = tid & 63;
  const int wv = tid >> 6, wr = wv >> 1, wc = wv & 1;
  const int lrow = lane & 15, lk = lane >> 4;
  __shared__ __align__(16) hb AsH[128 * 64];
  __shared__ __align__(16) hb AsL[128 * 64];
  __shared__ __align__(16) hb BsH[128 * 64];
  __shared__ __align__(16) hb BsL[128 * 64];

  const int srow = tid >> 3;
  const int sc8 = tid & 7;
  const int sslot = (sc8 - srow) & 7;

  f32x4 acc[4][4];
#pragma unroll
  for (int mi = 0; mi < 4; ++mi)
#pragma unroll
    for (int ni = 0; ni < 4; ++ni) acc[mi][ni] = (f32x4){0.f, 0.f, 0.f, 0.f};

  long long aoff[4], boff[4];
#pragma unroll
  for (int it = 0; it < 4; ++it) {
    int gm = bm + srow + it * 32; if (gm > M - 1) gm = M - 1;
    int gn = bn + srow + it * 32; if (gn > N - 1) gn = N - 1;
    aoff[it] = (long long)gm * lda + sslot * 8;
    boff[it] = (long long)gn * ldb + sslot * 8;
  }

  for (int k0 = 0; k0 < K; k0 += 64) {
#pragma unroll
    for (int it = 0; it < 4; ++it) {
      gload16(Ah + aoff[it] + k0, &AsH[(tid + it * 256) * 8]);
      gload16(Al + aoff[it] + k0, &AsL[(tid + it * 256) * 8]);
      gload16(Bh + boff[it] + k0, &BsH[(tid + it * 256) * 8]);
      gload16(Bl + boff[it] + k0, &BsL[(tid + it * 256) * 8]);
    }
    __syncthreads();
#pragma unroll
    for (int ks = 0; ks < 2; ++ks) {
      const int sa = ((ks * 4 + lk + lrow) & 7) * 8;
      short8 aH[4], aL[4], bH[4], bL[4];
#pragma unroll
      for (int mi = 0; mi < 4; ++mi) {
        int r = (wr * 64 + mi * 16 + lrow) * 64 + sa;
        aH[mi] = *(const short8*)&AsH[r];
        aL[mi] = *(const short8*)&AsL[r];
      }
#pragma unroll
      for (int ni = 0; ni < 4; ++ni) {
        int r = (wc * 64 + ni * 16 + lrow) * 64 + sa;
        bH[ni] = *(const short8*)&BsH[r];
        bL[ni] = *(const short8*)&BsL[r];
      }
#pragma unroll
      for (int mi = 0; mi < 4; ++mi)
#pragma unroll
        for (int ni = 0; ni < 4; ++ni) {
          acc[mi][ni] = __builtin_amdgcn_mfma_f32_16x16x32_bf16(
              aH[mi], bH[ni], acc[mi][ni], 0, 0, 0);
          acc[mi][ni] = __builtin_amdgcn_mfma_f32_16x16x32_bf16(
              aL[mi], bH[ni], acc[mi][ni], 0, 0, 0);
          acc[mi][ni] = __builtin_amdgcn_mfma_f32_16x16x32_bf16(
              aH[mi], bL[ni], acc[mi][ni], 0, 0, 0);
        }
    }
    __syncthreads();
  }

  float* Cf = (float*)Cv;
  hb* Cb = (hb*)Cv;
  hb* Cb2 = (hb*)Cv2;
#pragma unroll
  for (int mi = 0; mi < 4; ++mi) {
#pragma unroll
    for (int ni = 0; ni < 4; ++ni) {
#pragma unroll
      for (int q = 0; q < 4; ++q) {
        int gm = bm + wr * 64 + mi * 16 + lk * 4 + q;
        int gn = bn + wc * 64 + ni * 16 + lrow;
        if (gm < M && gn < N) {
          float v = acc[mi][ni][q];
          if (bias) v += bias[gn];
          if (act)  v = gelu_f(v);
          long long off = (long long)gm * ldc + gn;
          if (out_mode == 2) {
            unsigned short h = bf_bits(v);
            unsigned short l = bf_bits(v - bf_back(h));
            Cb[off] = *reinterpret_cast<hb*>(&h);
            Cb2[off] = *reinterpret_cast<hb*>(&l);
          } else {
            Cf[off] = v;
          }
        }
      }
    }
  }
}

// ---------------------------------------------------------------------------
// Banded MFMA: partial[kq][b][s][d] = proj[s].em[s+d] over K-quarter (3-term)
// ---------------------------------------------------------------------------
__global__ __launch_bounds__(256) void bandmm(
    const hb* __restrict__ Phi, const hb* __restrict__ Plo,
    const hb* __restrict__ Ehi, const hb* __restrict__ Elo,
    float* __restrict__ partial)
{
  const int s0 = blockIdx.x * 64;
  const int kq = blockIdx.y;
  const int b = blockIdx.z;
  const int tid = threadIdx.x;
  const int lane = tid & 63;
  const int wv = tid >> 6, wr = wv >> 1, wc = wv & 1;
  const int lrow = lane & 15, lk = lane >> 4;
  __shared__ __align__(16) hb As[64 * 64];
  __shared__ __align__(16) hb Bs[96 * 64];

  f32x4 acc[2][3];
#pragma unroll
  for (int mi = 0; mi < 2; ++mi)
#pragma unroll
    for (int ni = 0; ni < 3; ++ni) acc[mi][ni] = (f32x4){0.f, 0.f, 0.f, 0.f};

  const long long Pbase = (long long)(b * S_LEN) * FDIM;
  long long aoff[2], boff[3];
#pragma unroll
  for (int it = 0; it < 2; ++it) {
    int row = (tid + it * 256) >> 3;
    aoff[it] = Pbase + (long long)(s0 + row) * FDIM + (tid & 7) * 8;
  }
#pragma unroll
  for (int it = 0; it < 3; ++it) {
    int row = (tid + it * 256) >> 3;
    int t = s0 + row; if (t > S_LEN - 1) t = S_LEN - 1;
    boff[it] = Pbase + (long long)t * FDIM + (tid & 7) * 8;
  }

  const int kbeg = kq * (FDIM / 4), kend = kbeg + FDIM / 4;
  for (int t3 = 0; t3 < 3; ++t3) {
    const hb* Ap = (t3 == 1) ? Plo : Phi;
    const hb* Bp = (t3 == 2) ? Elo : Ehi;
    for (int k0 = kbeg; k0 < kend; k0 += 64) {
#pragma unroll
      for (int it = 0; it < 2; ++it)
        gload16(Ap + aoff[it] + k0, &As[(tid + it * 256) * 8]);
#pragma unroll
      for (int it = 0; it < 3; ++it)
        gload16(Bp + boff[it] + k0, &Bs[(tid + it * 256) * 8]);
      __syncthreads();
#pragma unroll
      for (int ks = 0; ks < 2; ++ks) {
        short8 a[2], bb[3];
#pragma unroll
        for (int mi = 0; mi < 2; ++mi)
          a[mi] = *(const short8*)&As[(wr * 32 + mi * 16 + lrow) * 64 + ks * 32 + lk * 8];
#pragma unroll
        for (int ni = 0; ni < 3; ++ni)
          bb[ni] = *(const short8*)&Bs[(wc * 48 + ni * 16 + lrow) * 64 + ks * 32 + lk * 8];
#pragma unroll
        for (int mi = 0; mi < 2; ++mi)
#pragma unroll
          for (int ni = 0; ni < 3; ++ni)
            acc[mi][ni] = __builtin_amdgcn_mfma_f32_16x16x32_bf16(
                a[mi], bb[ni], acc[mi][ni], 0, 0, 0);
      }
      __syncthreads();
    }
  }

#pragma unroll
  for (int mi = 0; mi < 2; ++mi) {
#pragma unroll
    for (int ni = 0; ni < 3; ++ni) {
#pragma unroll
      for (int q = 0; q < 4; ++q) {
        int i = wr * 32 + mi * 16 + lk * 4 + q;
        int n = wc * 48 + ni * 16 + lrow;
        int d = n - i;
        if (d >= 0 && d < 32) {
          long long off = (((long long)(kq * 2 + b)) * S_LEN + (s0 + i)) * 32 + d;
          partial[off] = acc[mi][ni][q];
        }
      }
    }
  }
}

// sum partials (fixed order), add ssc/esc, clip; -3e38 outside band
__global__ __launch_bounds__(256) void band_reduce(
    const float* __restrict__ partial, const float* __restrict__ ssc,
    const float* __restrict__ esc, float* __restrict__ band)
{
  int idx = blockIdx.x * 256 + threadIdx.x;
  if (idx >= BATCH * S_LEN * 32) return;
  int d = idx & 31;
  int s = (idx >> 5) & (S_LEN - 1);
  int b = idx >> 16;
  int t = s + d;
  float v;
  if (d < MAXSPAN && t < S_LEN) {
    float sum = 0.f;
#pragma unroll
    for (int kq = 0; kq < 4; ++kq)
      sum += partial[(((long long)(kq * 2 + b)) * S_LEN + s) * 32 + d];
    sum += ssc[b * S_LEN + s] + esc[b * S_LEN + t];
    v = fminf(fmaxf(sum, NEGV), -NEGV);
  } else {
    v = -3.0e38f;
  }
  band[idx] = v;
}

// ---------------------------------------------------------------------------
__global__ __launch_bounds__(256) void split_mat(
    const float* __restrict__ src, hb* __restrict__ hi, hb* __restrict__ lo,
    long long n4)
{
  long long i = (long long)blockIdx.x * 256 + threadIdx.x;
  if (i >= n4) return;
  float4 v = ((const float4*)src)[i];
  unsigned short h[4], l[4];
  float vv[4] = {v.x, v.y, v.z, v.w};
#pragma unroll
  for (int j = 0; j < 4; ++j) {
    h[j] = bf_bits(vv[j]);
    l[j] = bf_bits(vv[j] - bf_back(h[j]));
  }
  ((uint2*)hi)[i] = *(uint2*)h;
  ((uint2*)lo)[i] = *(uint2*)l;
}

// split + transpose: src f32 [K][N] -> hiT,loT bf16 [N][K]
__global__ __launch_bounds__(256) void splitT_mat(
    const float* __restrict__ src, hb* __restrict__ hiT, hb* __restrict__ loT,
    int K, int N)
{
  __shared__ float t[32][33];
  int k0 = blockIdx.y * 32, n0 = blockIdx.x * 32;
  int tx = threadIdx.x & 31, ty = threadIdx.x >> 5;
#pragma unroll
  for (int r = 0; r < 4; ++r)
    t[ty + r * 8][tx] = src[(long long)(k0 + ty + r * 8) * N + (n0 + tx)];
  __syncthreads();
#pragma unroll
  for (int r = 0; r < 4; ++r) {
    int n = n0 + ty + r * 8;
    float v = t[tx][ty + r * 8];
    unsigned short h = bf_bits(v);
    unsigned short l = bf_bits(v - bf_back(h));
    hiT[(long long)n * K + k0 + tx] = *reinterpret_cast<hb*>(&h);
    loT[(long long)n * K + k0 + tx] = *reinterpret_cast<hb*>(&l);
  }
}

// ---------------------------------------------------------------------------
// Fused LayerNorm (fp64 stats) + hi/lo bf16 split + cls row-dot (fp64 accum)
// ---------------------------------------------------------------------------
__global__ __launch_bounds__(256) void ln_split_dot(
    const float* __restrict__ src, hb* __restrict__ hi, hb* __restrict__ lo,
    const float* __restrict__ g, const float* __restrict__ be,
    const float* __restrict__ w, const float* __restrict__ wb,
    float* __restrict__ dot_out)
{
  __shared__ float row[FDIM];
  __shared__ double scr[4];
  __shared__ double sh_mu, sh_rstd;
  const long long r = blockIdx.x;
  const float* p = src + r * FDIM;
  const int tid = threadIdx.x;

  double s = 0.0;
#pragma unroll
  for (int pp = 0; pp < 3; ++pp) {
    int c4 = pp * 256 + tid;
    float4 v = *(const float4*)(p + c4 * 4);
    *(float4*)&row[c4 * 4] = v;
    s += (double)v.x + (double)v.y + (double)v.z + (double)v.w;
  }
#pragma unroll
  for (int off = 32; off; off >>= 1) s += __shfl_down(s, off, 64);
  if ((tid & 63) == 0) scr[tid >> 6] = s;
  __syncthreads();
  if (tid == 0) sh_mu = (scr[0] + scr[1] + scr[2] + scr[3]) / FDIM;
  __syncthreads();
  double mu = sh_mu;
  double vs = 0.0;
#pragma unroll
  for (int pp = 0; pp < 12; ++pp) {
    double d = (double)row[pp * 256 + tid] - mu;
    vs += d * d;
  }
#pragma unroll
  for (int off = 32; off; off >>= 1) vs += __shfl_down(vs, off, 64);
  __syncthreads();
  if ((tid & 63) == 0) scr[tid >> 6] = vs;
  __syncthreads();
  if (tid == 0)
    sh_rstd = 1.0 / sqrt((scr[0] + scr[1] + scr[2] + scr[3]) / FDIM + 1e-5);
  __syncthreads();
  double rstd = sh_rstd;

  double dot = 0.0;
#pragma unroll
  for (int pp = 0; pp < 3; ++pp) {
    int c4 = pp * 256 + tid;
    float4 gv = *(const float4*)(g + c4 * 4);
    float4 bv = *(const float4*)(be + c4 * 4);
    float4 wv = *(const float4*)(w + c4 * 4);
    float xv[4];
    *(float4*)xv = *(const float4*)&row[c4 * 4];
    unsigned short hh[4], ll[4];
    float gg[4] = {gv.x, gv.y, gv.z, gv.w};
    float bb[4] = {bv.x, bv.y, bv.z, bv.w};
    float ww[4] = {wv.x, wv.y, wv.z, wv.w};
#pragma unroll
    for (int j = 0; j < 4; ++j) {
      float val = (float)(((double)xv[j] - mu) * rstd * (double)gg[j] + (double)bb[j]);
      dot += (double)val * (double)ww[j];
      hh[j] = bf_bits(val);
      ll[j] = bf_bits(val - bf_back(hh[j]));
    }
    *(uint2*)(hi + r * FDIM + c4 * 4) = *(uint2*)hh;
    *(uint2*)(lo + r * FDIM + c4 * 4) = *(uint2*)ll;
  }
#pragma unroll
  for (int off = 32; off; off >>= 1) dot += __shfl_down(dot, off, 64);
  __syncthreads();
  if ((tid & 63) == 0) scr[tid >> 6] = dot;
  __syncthreads();
  if (tid == 0)
    dot_out[r] = (float)(scr[0] + scr[1] + scr[2] + scr[3] + (double)wb[0]);
}

// LayerNorm f32 src -> bf16 dst (phase-2)
__global__ __launch_bounds__(256) void ln_rows_bf(
    const float* __restrict__ src, hb* __restrict__ dst,
    const float* __restrict__ g, const float* __restrict__ be,
    int n, long long lds_, long long ldd)
{
  long long r = blockIdx.x;
  const float* p = src + r * lds_;
  hb* d = dst + r * ldd;
  __shared__ double scratch[4];
  __shared__ double sh_mu, sh_rstd;
  double s = 0.0;
  for (int c = threadIdx.x; c < n; c += 256) s += (double)p[c];
#pragma unroll
  for (int off = 32; off; off >>= 1) s += __shfl_down(s, off, 64);
  if ((threadIdx.x & 63) == 0) scratch[threadIdx.x >> 6] = s;
  __syncthreads();
  if (threadIdx.x == 0) sh_mu = (scratch[0] + scratch[1] + scratch[2] + scratch[3]) / n;
  __syncthreads();
  double mu = sh_mu;
  double vs = 0.0;
  for (int c = threadIdx.x; c < n; c += 256) { double dd = (double)p[c] - mu; vs += dd * dd; }
#pragma unroll
  for (int off = 32; off; off >>= 1) vs += __shfl_down(vs, off, 64);
  __syncthreads();
  if ((threadIdx.x & 63) == 0) scratch[threadIdx.x >> 6] = vs;
  __syncthreads();
  if (threadIdx.x == 0)
    sh_rstd = 1.0 / sqrt((scratch[0] + scratch[1] + scratch[2] + scratch[3]) / n + 1e-5);
  __syncthreads();
  double rstd = sh_rstd;
  for (int c = threadIdx.x; c < n; c += 256)
    d[c] = __float2bfloat16(
        (float)(((double)p[c] - mu) * rstd * (double)g[c] + (double)be[c]));
}

// ---------------------------------------------------------------------------
// Top-k selection (radix on monotone float keys) + index sort, 1 block/batch
// ---------------------------------------------------------------------------
__device__ __forceinline__ unsigned f2k(float f) {
  unsigned u = __float_as_uint(f);
  return (u & 0x80000000u) ? ~u : (u | 0x80000000u);
}

__device__ void bitonic1024(int* a) {
  const int tid = threadIdx.x;
  for (int sz = 2; sz <= 1024; sz <<= 1) {
    for (int st = sz >> 1; st > 0; st >>= 1) {
      __syncthreads();
      int j = tid ^ st;
      if (j > tid) {
        int x = a[tid], y = a[j];
        bool asc = (tid & sz) == 0;
        if ((x > y) == asc) { a[tid] = y; a[j] = x; }
      }
    }
  }
  __syncthreads();
}

__global__ __launch_bounds__(1024) void select_sort(
    const float* __restrict__ band, const int* __restrict__ masks,
    int* __restrict__ sidx, int* __restrict__ starts, int* __restrict__ ends,
    float* __restrict__ tms, int* __restrict__ kvals)
{
  const int b = blockIdx.x;
  const int tid = threadIdx.x;
  __shared__ int hist[256];
  __shared__ int sel[1024];
  __shared__ int eq[1024];
  __shared__ int sred[16];
  __shared__ int cvar[4];
  __shared__ int cnt_gt, cnt_eq;

  int msum = 0;
  for (int i = tid; i < S_LEN; i += 1024) msum += masks[b * S_LEN + i];
#pragma unroll
  for (int off = 32; off; off >>= 1) msum += __shfl_down(msum, off, 64);
  if ((tid & 63) == 0) sred[tid >> 6] = msum;
  __syncthreads();
  if (tid == 0) {
    int t = 0;
    for (int w = 0; w < 16; ++w) t += sred[w];
    cvar[2] = t;
  }
  __syncthreads();
  int kv = (int)((float)cvar[2] * 0.4f);
  if (kv > MAXK) kv = MAXK;
  if (kv < 0) kv = 0;

  const int NC = S_LEN * MAXSPAN;
  unsigned prefix = 0u;
  int remaining = kv;

  if (kv > 0) {
    for (int byte = 3; byte >= 0; --byte) {
      if (tid < 256) hist[tid] = 0;
      __syncthreads();
      for (int i = tid; i < NC; i += 1024) {
        int s = i / MAXSPAN;
        int d = i - s * MAXSPAN;
        float v = band[((long long)(b * S_LEN + s)) * 32 + d];
        unsigned key = f2k(v);
        bool match = (byte == 3) ||
            ((key >> ((byte + 1) * 8)) == (prefix >> ((byte + 1) * 8)));
        if (match) atomicAdd(&hist[(key >> (byte * 8)) & 255], 1);
      }
      __syncthreads();
      if (tid == 0) {
        int cum = 0, chosen = 255;
        for (int v = 255; v >= 0; --v) {
          int h = hist[v];
          if (cum + h >= remaining) { chosen = v; cvar[0] = remaining - cum; break; }
          cum += h;
        }
        cvar[1] = chosen;
      }
      __syncthreads();
      remaining = cvar[0];
      prefix |= ((unsigned)cvar[1]) << (byte * 8);
      __syncthreads();
    }
    if (tid == 0) { cnt_gt = 0; cnt_eq = 0; }
    __syncthreads();
    for (int i = tid; i < NC; i += 1024) {
      int s = i / MAXSPAN;
      int d = i - s * MAXSPAN;
      float v = band[((long long)(b * S_LEN + s)) * 32 + d];
      unsigned key = f2k(v);
      int flat = s * S_LEN + s + d;
      if (key > prefix) {
        int p = atomicAdd(&cnt_gt, 1);
        if (p < MAXK) sel[p] = flat;
      } else if (key == prefix) {
        int p = atomicAdd(&cnt_eq, 1);
        if (p < 1024) eq[p] = flat;
      }
    }
    __syncthreads();
    int ngt = cnt_gt;
    int neq = cnt_eq; if (neq > 1024) neq = 1024;
    if (tid >= neq) eq[tid] = 0x7FFFFFFF;
    __syncthreads();
    bitonic1024(eq);
    int need = kv - ngt;
    if (tid < need) sel[ngt + tid] = eq[tid];
    __syncthreads();
  }
  if (tid >= kv && tid < MAXK) sel[tid] = S_LEN * S_LEN - 1;
  if (tid >= MAXK) sel[tid] = 0x7FFFFFFF;
  __syncthreads();
  bitonic1024(sel);
  if (tid < MAXK) {
    int idx = sel[tid];
    int s = idx >> 11;
    int t = idx & (S_LEN - 1);
    sidx[b * MAXK + tid] = idx;
    starts[b * MAXK + tid] = s;
    ends[b * MAXK + tid] = t;
    tms[b * MAXK + tid] = band[((long long)(b * S_LEN + s)) * 32 + (t - s)];
  }
  if (tid == 0) kvals[b] = kv;
}

// dst[b*MAXK+j, :] = bf16(src[b, rows[b*MAXK+j], :])   (H = 1024)
__global__ __launch_bounds__(256) void gather_bf(
    const float* __restrict__ src, const int* __restrict__ rows,
    hb* __restrict__ dst)
{
  int g = blockIdx.x;
  int b = g / MAXK;
  int r = rows[g];
  const float4* s4 = (const float4*)(src + ((long long)(b * S_LEN + r)) * HDIM);
  hb* d = dst + (long long)g * HDIM;
  float4 v = s4[threadIdx.x];
  d[threadIdx.x * 4 + 0] = __float2bfloat16(v.x);
  d[threadIdx.x * 4 + 1] = __float2bfloat16(v.y);
  d[threadIdx.x * 4 + 2] = __float2bfloat16(v.z);
  d[threadIdx.x * 4 + 3] = __float2bfloat16(v.w);
}

// transpose+convert: dst[n][koff + k] (bf16, row stride ldd) = src[k][n] (f32)
__global__ __launch_bounds__(256) void conv_t(
    const float* __restrict__ src, hb* __restrict__ dst,
    int K, int N, int koff, int ldd)
{
  __shared__ float t[32][33];
  int k0 = blockIdx.y * 32, n0 = blockIdx.x * 32;
  int tx = threadIdx.x & 31, ty = threadIdx.x >> 5;
#pragma unroll
  for (int r = 0; r < 4; ++r)
    t[ty + r * 8][tx] = src[(long long)(k0 + ty + r * 8) * N + (n0 + tx)];
  __syncthreads();
#pragma unroll
  for (int r = 0; r < 4; ++r) {
    int n = n0 + ty + r * 8;
    dst[(long long)n * ldd + koff + k0 + tx] = __float2bfloat16(t[tx][ty + r * 8]);
  }
}

__global__ __launch_bounds__(256) void add2(
    const float* __restrict__ a, const float* __restrict__ b,
    float* __restrict__ c, int n)
{
  int i = blockIdx.x * 256 + threadIdx.x;
  if (i < n) c[i] = a[i] + b[i];
}

// out[b,i,j] assembly: sum 4 coref K-slices + pair + anaphora mask, zero last col
__global__ __launch_bounds__(256) void final_assemble(
    const float* __restrict__ coref4, const float* __restrict__ tms,
    const int* __restrict__ kvals, float* __restrict__ out)
{
  const long long SL = (long long)MAXK * MAXK;   // slice stride
  int g = blockIdx.x;                   // b*MAXK + i
  int b = g / MAXK;
  int i = g - b * MAXK;
  int kv = kvals[b];
  float ti = tms[g];
  const float* crow = coref4 + (long long)(b * 4) * SL + (long long)i * MAXK;
  float* orow = out + (long long)b * MAXK * (MAXK + 1) + (long long)i * (MAXK + 1);
  for (int j = threadIdx.x; j < MAXK + 1; j += 256) {
    float v;
    if (j == MAXK) v = 0.f;
    else {
      float c = ((crow[j] + crow[j + SL]) + (crow[j + 2 * SL] + crow[j + 3 * SL]));
      v = ti + tms[b * MAXK + j] + c;
      if (!((j < i) && (i < kv))) v += NEGV;
      v = fminf(fmaxf(v, NEGV), -NEGV);
    }
    orow[j] = v;
  }
}

// ---------------------------------------------------------------------------
static inline void launch1(const hb* A, const hb* B, const float* bias, void* C,
    int M, int N, int K, int lda, int ldb, int ldc,
    long long sA, long long sB, long long sC,
    int act, int out_mode, int zcount, int kspl, hipStream_t stream)
{
  dim3 grid((N + 127) / 128, (M + 127) / 128, zcount);
  gemm_fast1<<<grid, 256, 0, stream>>>(A, B, bias, C, M, N, K, lda, ldb, ldc,
                                       sA, sB, sC, act, out_mode, kspl);
}

static inline void launch3(const hb* Ah, const hb* Al, const hb* Bh, const hb* Bl,
    const float* bias, void* C, void* C2, int M, int N, int K,
    int lda, int ldb, int ldc, int act, int out_mode, hipStream_t stream)
{
  dim3 grid((N + 127) / 128, (M + 127) / 128, 1);
  gemm_fast3<<<grid, 256, 0, stream>>>(Ah, Al, Bh, Bl, bias, C, C2,
                                       M, N, K, lda, ldb, ldc, act, out_mode);
}

extern "C" void kernel_launch(void* const* d_in, const int* in_sizes, int n_in,
                              void* d_out, int out_size, void* d_ws, size_t ws_size,
                              hipStream_t stream) {
  const float* input_emb = (const float*)d_in[0];
  const int*   input_masks = (const int*)d_in[1];
  const float* sm_W = (const float*)d_in[2];
  const float* sm_b = (const float*)d_in[3];
  const float* sm_g = (const float*)d_in[4];
  const float* sm_be = (const float*)d_in[5];
  const float* em_W = (const float*)d_in[6];
  const float* em_b = (const float*)d_in[7];
  const float* em_g = (const float*)d_in[8];
  const float* em_be = (const float*)d_in[9];
  const float* sc_W = (const float*)d_in[10];
  const float* sc_b = (const float*)d_in[11];
  const float* sc_g = (const float*)d_in[12];
  const float* sc_be = (const float*)d_in[13];
  const float* ec_W = (const float*)d_in[14];
  const float* ec_b = (const float*)d_in[15];
  const float* ec_g = (const float*)d_in[16];
  const float* ec_be = (const float*)d_in[17];
  const float* cls_s_W = (const float*)d_in[18];
  const float* cls_s_b = (const float*)d_in[19];
  const float* cls_e_W = (const float*)d_in[20];
  const float* cls_e_b = (const float*)d_in[21];
  const float* s2e_W = (const float*)d_in[22];
  const float* s2e_b = (const float*)d_in[23];
  const float* a_ss_W = (const float*)d_in[24];
  const float* a_ss_b = (const float*)d_in[25];
  const float* a_ee_W = (const float*)d_in[26];
  const float* a_ee_b = (const float*)d_in[27];
  const float* a_se_W = (const float*)d_in[28];
  const float* a_se_b = (const float*)d_in[29];
  const float* a_es_W = (const float*)d_in[30];
  const float* a_es_b = (const float*)d_in[31];
  float* out = (float*)d_out;

  const int NROW = BATCH * S_LEN;           // 4096
  const int MROW = BATCH * MAXK;            // 1638
  const long long SZ_BIG = (long long)NROW * FDIM * 4;      // 50331648

  char* ws = (char*)d_ws;
  // ---- phase-1 regions (schedule in launch order) ----
  float* smF    = (float*)(ws);                     // sm f32, dead after LN
  hb* sm_hi     = (hb*)(ws + 50331648LL);
  hb* sm_lo     = (hb*)(ws + 75497472LL);
  hb* emb_hi    = (hb*)(ws + 100663296LL);
  hb* emb_lo    = (hb*)(ws + 109051904LL);
  hb* w1_hiT    = (hb*)(ws + 117440512LL);
  hb* w1_loT    = (hb*)(ws + 123731968LL);
  hb* s2e_hiT   = (hb*)(ws);                        // after smF dead
  hb* s2e_loT   = (hb*)(ws + 18874368LL);
  hb* proj_hi   = (hb*)(ws + 100663296LL);          // after emb/w1 dead
  hb* proj_lo   = (hb*)(ws + 125829120LL);
  hb* emb2_hi   = (hb*)(ws);                        // after s2eT dead
  hb* emb2_lo   = (hb*)(ws + 8388608LL);
  hb* w2_hiT    = (hb*)(ws + 16777216LL);
  hb* w2_loT    = (hb*)(ws + 23068672LL);
  float* emF    = (float*)(ws + 50331648LL);        // after sm splits dead
  hb* em_hi     = (hb*)(ws);                        // after emb2/w2 dead
  hb* em_lo     = (hb*)(ws + 25165824LL);
  float* partial = (float*)(ws + 50331648LL);       // after emF dead, 2 MB
  // ---- phase-2 overlay ----
  hb* tkcat = (hb*)(ws);                            // [1638][6144]
  hb* qcat  = (hb*)(ws + 20127744LL);
  float* mlp_s = (float*)(ws + 40255488LL);
  float* mlp_e = (float*)(ws + 60383232LL);
  hb* Xs_bf = (hb*)(ws + 80510976LL);
  hb* Xe_bf = (hb*)(ws + 83865600LL);
  hb* scWt  = (hb*)(ws + 87220224LL);
  hb* ecWt  = (hb*)(ws + 93511680LL);
  float* coref4 = (float*)(ws + 99803136LL);        // [2][4][819][819] f32, 21.5 MB
  hb* Wq1t = (hb*)(ws + 40255488LL);                // [3072][6144]
  hb* Wq2t = (hb*)(ws + 78004224LL);                // contiguous after Wq1t
  // ---- persistent tail ----
  const long long P = 3 * SZ_BIG;                   // 150994944
  float* band = (float*)(ws + P);
  float* ssc  = (float*)(ws + P + 524288);
  float* esc  = (float*)(ws + P + 540672);
  int* sidx   = (int*)(ws + P + 557056);
  int* starts = (int*)(ws + P + 565248);
  int* ends   = (int*)(ws + P + 573440);
  float* tms  = (float*)(ws + P + 581632);
  int* kvals  = (int*)(ws + P + 589824);
  float* biasq1 = (float*)(ws + P + 590080);        // [3072]
  float* biasq2 = (float*)(ws + P + 602368);        // contiguous -> [6144] cat
  if (ws_size < (size_t)(P + 614656)) return;

  const long long n4_emb = (long long)NROW * HDIM / 4;

  // ---- phase 1: selection-critical chain ----
  split_mat<<<(int)((n4_emb + 255) / 256), 256, 0, stream>>>(input_emb, emb_hi, emb_lo, n4_emb);
  splitT_mat<<<dim3(FDIM / 32, HDIM / 32), 256, 0, stream>>>(sm_W, w1_hiT, w1_loT, HDIM, FDIM);
  launch3(emb_hi, emb_lo, w1_hiT, w1_loT, sm_b, smF, nullptr,
          NROW, FDIM, HDIM, HDIM, HDIM, FDIM, 1, 0, stream);
  ln_split_dot<<<NROW, 256, 0, stream>>>(smF, sm_hi, sm_lo, sm_g, sm_be,
                                         cls_s_W, cls_s_b, ssc);
  splitT_mat<<<dim3(FDIM / 32, FDIM / 32), 256, 0, stream>>>(s2e_W, s2e_hiT, s2e_loT, FDIM, FDIM);
  launch3(sm_hi, sm_lo, s2e_hiT, s2e_loT, s2e_b, proj_hi, proj_lo,
          NROW, FDIM, FDIM, FDIM, FDIM, FDIM, 0, 2, stream);
  split_mat<<<(int)((n4_emb + 255) / 256), 256, 0, stream>>>(input_emb, emb2_hi, emb2_lo, n4_emb);
  splitT_mat<<<dim3(FDIM / 32, HDIM / 32), 256, 0, stream>>>(em_W, w2_hiT, w2_loT, HDIM, FDIM);
  launch3(emb2_hi, emb2_lo, w2_hiT, w2_loT, em_b, emF, nullptr,
          NROW, FDIM, HDIM, HDIM, HDIM, FDIM, 1, 0, stream);
  ln_split_dot<<<NROW, 256, 0, stream>>>(emF, em_hi, em_lo, em_g, em_be,
                                         cls_e_W, cls_e_b, esc);
  bandmm<<<dim3(S_LEN / 64, 4, BATCH), 256, 0, stream>>>(proj_hi, proj_lo, em_hi, em_lo, partial);
  band_reduce<<<(BATCH * S_LEN * 32) / 256, 256, 0, stream>>>(partial, ssc, esc, band);
  select_sort<<<BATCH, 1024, 0, stream>>>(band, input_masks, sidx, starts, ends, tms, kvals);

  // ---- phase 2: gathered coref reps, bf16 MFMA ----
  gather_bf<<<MROW, 256, 0, stream>>>(input_emb, starts, Xs_bf);
  gather_bf<<<MROW, 256, 0, stream>>>(input_emb, ends, Xe_bf);

  conv_t<<<dim3(FDIM / 32, HDIM / 32), 256, 0, stream>>>(sc_W, scWt, HDIM, FDIM, 0, HDIM);
  conv_t<<<dim3(FDIM / 32, HDIM / 32), 256, 0, stream>>>(ec_W, ecWt, HDIM, FDIM, 0, HDIM);

  launch1(Xs_bf, scWt, sc_b, mlp_s, MROW, FDIM, HDIM, HDIM, HDIM, FDIM,
          0, 0, 0, 1, 0, 1, 1, stream);
  launch1(Xe_bf, ecWt, ec_b, mlp_e, MROW, FDIM, HDIM, HDIM, HDIM, FDIM,
          0, 0, 0, 1, 0, 1, 1, stream);

  ln_rows_bf<<<MROW, 256, 0, stream>>>(mlp_s, tkcat, sc_g, sc_be, FDIM, FDIM, 2 * FDIM);
  ln_rows_bf<<<MROW, 256, 0, stream>>>(mlp_e, tkcat + FDIM, ec_g, ec_be, FDIM, FDIM, 2 * FDIM);

  conv_t<<<dim3(FDIM / 32, FDIM / 32), 256, 0, stream>>>(a_ss_W, Wq1t, FDIM, FDIM, 0,    2 * FDIM);
  conv_t<<<dim3(FDIM / 32, FDIM / 32), 256, 0, stream>>>(a_es_W, Wq1t, FDIM, FDIM, FDIM, 2 * FDIM);
  conv_t<<<dim3(FDIM / 32, FDIM / 32), 256, 0, stream>>>(a_se_W, Wq2t, FDIM, FDIM, 0,    2 * FDIM);
  conv_t<<<dim3(FDIM / 32, FDIM / 32), 256, 0, stream>>>(a_ee_W, Wq2t, FDIM, FDIM, FDIM, 2 * FDIM);
  add2<<<FDIM / 256, 256, 0, stream>>>(a_ss_b, a_es_b, biasq1, FDIM);
  add2<<<FDIM / 256, 256, 0, stream>>>(a_se_b, a_ee_b, biasq2, FDIM);

  // fused qcat: N = 6144 over contiguous [Wq1t; Wq2t] and [biasq1|biasq2]
  launch1(tkcat, Wq1t, biasq1, qcat, MROW, 2 * FDIM, 2 * FDIM,
          2 * FDIM, 2 * FDIM, 2 * FDIM, 0, 0, 0, 0, 1, 1, 1, stream);

  // coref: split-K x4 (K=1536/slice), batched z = b*4 + ks
  launch1(qcat, tkcat, nullptr, coref4, MAXK, MAXK, 1536,
          2 * FDIM, 2 * FDIM, MAXK,
          (long long)MAXK * 2 * FDIM, (long long)MAXK * 2 * FDIM,
          (long long)MAXK * MAXK, 0, 0, BATCH * 4, 4, stream);

  final_assemble<<<MROW, 256, 0, stream>>>(coref4, tms, kvals, out);
}

// Round 3
// 1243.767 us; speedup vs baseline: 1.1315x; 1.0320x over previous
//
#include <hip/hip_runtime.h>
#include <hip/hip_bf16.h>
#include <math.h>

#define S_LEN 2048
#define BATCH 2
#define HDIM 1024
#define FDIM 3072
#define MAXK 819
#define MAXSPAN 30
#define NEGV -10000.0f

typedef __attribute__((ext_vector_type(8))) short short8;
typedef __attribute__((ext_vector_type(4))) float f32x4;
typedef __hip_bfloat16 hb;

__device__ __forceinline__ float gelu_f(float x) {
  return 0.5f * x * (1.0f + erff(x * 0.70710678118654752440f));
}

__device__ __forceinline__ unsigned short bf_bits(float x) {
  hb b = __float2bfloat16(x);
  return *reinterpret_cast<unsigned short*>(&b);
}
__device__ __forceinline__ float bf_back(unsigned short u) {
  hb b = *reinterpret_cast<hb*>(&u);
  return __bfloat162float(b);
}

__device__ __forceinline__ void gload16(const void* g, void* l) {
  __builtin_amdgcn_global_load_lds(
      (const __attribute__((address_space(1))) void*)g,
      (__attribute__((address_space(3))) void*)l, 16, 0, 0);
}

// ---------------------------------------------------------------------------
// bf16 MFMA GEMM, single-term, BK=128 (128 MFMA per barrier-pair).
// C[M,N] = act(A[M,K] @ B[N,K]^T + bias).  K multiple of 128.
// z-batching: blockIdx.z = zb*kspl + zk; operands at zb*sA/sB, k-slice zk,
// C slice at blockIdx.z * sC.  bias2 (if non-null) replaces bias for zb>=1.
// Swizzled LDS slots (16 x 16B per row), linear gload_lds dest.
// out_mode: 0 = f32, 1 = bf16.
// NOTE: XCD-chunked blockIdx remap was tried (r1/r2) and REGRESSED here:
// inputs are L3-resident and kernel is not HBM-bound; chunking de-correlates
// the XCDs' B-panel streams (FETCH 240->326 MB). Keep default dispatch order.
// ---------------------------------------------------------------------------
__global__ __launch_bounds__(256) void gemm_fast1(
    const hb* __restrict__ A, const hb* __restrict__ B,
    const float* __restrict__ bias, const float* __restrict__ bias2,
    void* __restrict__ Cv,
    int M, int N, int K, int lda, int ldb, int ldc,
    long long sA, long long sB, long long sC,
    int act, int out_mode, int kspl)
{
  const int zb = blockIdx.z / kspl, zk = blockIdx.z - zb * kspl;
  A += (long long)zb * sA + (long long)zk * K;
  B += (long long)zb * sB + (long long)zk * K;
  const long long cbase = (long long)blockIdx.z * sC;
  const float* bp = (bias2 && zb) ? bias2 : bias;
  const int bm = blockIdx.y * 128, bn = blockIdx.x * 128;
  const int tid = threadIdx.x;
  const int lane = tid & 63;
  const int wv = tid >> 6, wr = wv >> 1, wc = wv & 1;
  const int lrow = lane & 15, lk = lane >> 4;
  __shared__ __align__(16) hb As[128 * 128];
  __shared__ __align__(16) hb Bs[128 * 128];

  const int srow = tid >> 4;          // 0..15
  const int sc8 = tid & 15;           // 16 slots of 8 bf16
  const int sslot = (sc8 - srow) & 15;  // inverse swizzle on global source

  f32x4 acc[4][4];
#pragma unroll
  for (int mi = 0; mi < 4; ++mi)
#pragma unroll
    for (int ni = 0; ni < 4; ++ni) acc[mi][ni] = (f32x4){0.f, 0.f, 0.f, 0.f};

  long long aoff[8], boff[8];
#pragma unroll
  for (int it = 0; it < 8; ++it) {
    int gm = bm + srow + it * 16; if (gm > M - 1) gm = M - 1;
    int gn = bn + srow + it * 16; if (gn > N - 1) gn = N - 1;
    aoff[it] = (long long)gm * lda + sslot * 8;
    boff[it] = (long long)gn * ldb + sslot * 8;
  }

  for (int k0 = 0; k0 < K; k0 += 128) {
#pragma unroll
    for (int it = 0; it < 8; ++it)
      gload16(A + aoff[it] + k0, &As[(tid + it * 256) * 8]);
#pragma unroll
    for (int it = 0; it < 8; ++it)
      gload16(B + boff[it] + k0, &Bs[(tid + it * 256) * 8]);
    __syncthreads();
#pragma unroll
    for (int ks = 0; ks < 4; ++ks) {
      const int sa = ((ks * 4 + lk + lrow) & 15) * 8;   // swizzled read slot
      short8 a[4], b[4];
#pragma unroll
      for (int mi = 0; mi < 4; ++mi)
        a[mi] = *(const short8*)&As[(wr * 64 + mi * 16 + lrow) * 128 + sa];
#pragma unroll
      for (int ni = 0; ni < 4; ++ni)
        b[ni] = *(const short8*)&Bs[(wc * 64 + ni * 16 + lrow) * 128 + sa];
#pragma unroll
      for (int mi = 0; mi < 4; ++mi)
#pragma unroll
        for (int ni = 0; ni < 4; ++ni)
          acc[mi][ni] = __builtin_amdgcn_mfma_f32_16x16x32_bf16(
              a[mi], b[ni], acc[mi][ni], 0, 0, 0);
    }
    __syncthreads();
  }

  float* Cf = (float*)Cv;
  hb* Cb = (hb*)Cv;
#pragma unroll
  for (int mi = 0; mi < 4; ++mi) {
#pragma unroll
    for (int ni = 0; ni < 4; ++ni) {
#pragma unroll
      for (int q = 0; q < 4; ++q) {
        int gm = bm + wr * 64 + mi * 16 + lk * 4 + q;
        int gn = bn + wc * 64 + ni * 16 + lrow;
        if (gm < M && gn < N) {
          float v = acc[mi][ni][q];
          if (bp)   v += bp[gn];
          if (act)  v = gelu_f(v);
          long long off = cbase + (long long)gm * ldc + gn;
          if (out_mode == 1) Cb[off] = __float2bfloat16(v);
          else               Cf[off] = v;
        }
      }
    }
  }
}

// ---------------------------------------------------------------------------
// Fused split-bf16 3-term GEMM (fp32-equivalent): stages A_hi,A_lo,B_hi,B_lo
// once per K-tile (64KB LDS), 96 MFMAs per K-tile (hh + lh + hl). BK=64.
// out_mode: 0 = f32, 2 = split hi/lo bf16.
// ---------------------------------------------------------------------------
__global__ __launch_bounds__(256) void gemm_fast3(
    const hb* __restrict__ Ah, const hb* __restrict__ Al,
    const hb* __restrict__ Bh, const hb* __restrict__ Bl,
    const float* __restrict__ bias, void* __restrict__ Cv, void* __restrict__ Cv2,
    int M, int N, int K, int lda, int ldb, int ldc, int act, int out_mode)
{
  const int bm = blockIdx.y * 128, bn = blockIdx.x * 128;
  const int tid = threadIdx.x;
  const int lane = tid & 63;
  const int wv = tid >> 6, wr = wv >> 1, wc = wv & 1;
  const int lrow = lane & 15, lk = lane >> 4;
  __shared__ __align__(16) hb AsH[128 * 64];
  __shared__ __align__(16) hb AsL[128 * 64];
  __shared__ __align__(16) hb BsH[128 * 64];
  __shared__ __align__(16) hb BsL[128 * 64];

  const int srow = tid >> 3;
  const int sc8 = tid & 7;
  const int sslot = (sc8 - srow) & 7;

  f32x4 acc[4][4];
#pragma unroll
  for (int mi = 0; mi < 4; ++mi)
#pragma unroll
    for (int ni = 0; ni < 4; ++ni) acc[mi][ni] = (f32x4){0.f, 0.f, 0.f, 0.f};

  long long aoff[4], boff[4];
#pragma unroll
  for (int it = 0; it < 4; ++it) {
    int gm = bm + srow + it * 32; if (gm > M - 1) gm = M - 1;
    int gn = bn + srow + it * 32; if (gn > N - 1) gn = N - 1;
    aoff[it] = (long long)gm * lda + sslot * 8;
    boff[it] = (long long)gn * ldb + sslot * 8;
  }

  for (int k0 = 0; k0 < K; k0 += 64) {
#pragma unroll
    for (int it = 0; it < 4; ++it) {
      gload16(Ah + aoff[it] + k0, &AsH[(tid + it * 256) * 8]);
      gload16(Al + aoff[it] + k0, &AsL[(tid + it * 256) * 8]);
      gload16(Bh + boff[it] + k0, &BsH[(tid + it * 256) * 8]);
      gload16(Bl + boff[it] + k0, &BsL[(tid + it * 256) * 8]);
    }
    __syncthreads();
#pragma unroll
    for (int ks = 0; ks < 2; ++ks) {
      const int sa = ((ks * 4 + lk + lrow) & 7) * 8;
      short8 aH[4], aL[4], bH[4], bL[4];
#pragma unroll
      for (int mi = 0; mi < 4; ++mi) {
        int r = (wr * 64 + mi * 16 + lrow) * 64 + sa;
        aH[mi] = *(const short8*)&AsH[r];
        aL[mi] = *(const short8*)&AsL[r];
      }
#pragma unroll
      for (int ni = 0; ni < 4; ++ni) {
        int r = (wc * 64 + ni * 16 + lrow) * 64 + sa;
        bH[ni] = *(const short8*)&BsH[r];
        bL[ni] = *(const short8*)&BsL[r];
      }
#pragma unroll
      for (int mi = 0; mi < 4; ++mi)
#pragma unroll
        for (int ni = 0; ni < 4; ++ni) {
          acc[mi][ni] = __builtin_amdgcn_mfma_f32_16x16x32_bf16(
              aH[mi], bH[ni], acc[mi][ni], 0, 0, 0);
          acc[mi][ni] = __builtin_amdgcn_mfma_f32_16x16x32_bf16(
              aL[mi], bH[ni], acc[mi][ni], 0, 0, 0);
          acc[mi][ni] = __builtin_amdgcn_mfma_f32_16x16x32_bf16(
              aH[mi], bL[ni], acc[mi][ni], 0, 0, 0);
        }
    }
    __syncthreads();
  }

  float* Cf = (float*)Cv;
  hb* Cb = (hb*)Cv;
  hb* Cb2 = (hb*)Cv2;
#pragma unroll
  for (int mi = 0; mi < 4; ++mi) {
#pragma unroll
    for (int ni = 0; ni < 4; ++ni) {
#pragma unroll
      for (int q = 0; q < 4; ++q) {
        int gm = bm + wr * 64 + mi * 16 + lk * 4 + q;
        int gn = bn + wc * 64 + ni * 16 + lrow;
        if (gm < M && gn < N) {
          float v = acc[mi][ni][q];
          if (bias) v += bias[gn];
          if (act)  v = gelu_f(v);
          long long off = (long long)gm * ldc + gn;
          if (out_mode == 2) {
            unsigned short h = bf_bits(v);
            unsigned short l = bf_bits(v - bf_back(h));
            Cb[off] = *reinterpret_cast<hb*>(&h);
            Cb2[off] = *reinterpret_cast<hb*>(&l);
          } else {
            Cf[off] = v;
          }
        }
      }
    }
  }
}

// ---------------------------------------------------------------------------
// Banded MFMA: partial[kq][b][s][d] = proj[s].em[s+d] over K-quarter (3-term)
// ---------------------------------------------------------------------------
__global__ __launch_bounds__(256) void bandmm(
    const hb* __restrict__ Phi, const hb* __restrict__ Plo,
    const hb* __restrict__ Ehi, const hb* __restrict__ Elo,
    float* __restrict__ partial)
{
  const int s0 = blockIdx.x * 64;
  const int kq = blockIdx.y;
  const int b = blockIdx.z;
  const int tid = threadIdx.x;
  const int lane = tid & 63;
  const int wv = tid >> 6, wr = wv >> 1, wc = wv & 1;
  const int lrow = lane & 15, lk = lane >> 4;
  __shared__ __align__(16) hb As[64 * 64];
  __shared__ __align__(16) hb Bs[96 * 64];

  f32x4 acc[2][3];
#pragma unroll
  for (int mi = 0; mi < 2; ++mi)
#pragma unroll
    for (int ni = 0; ni < 3; ++ni) acc[mi][ni] = (f32x4){0.f, 0.f, 0.f, 0.f};

  const long long Pbase = (long long)(b * S_LEN) * FDIM;
  long long aoff[2], boff[3];
#pragma unroll
  for (int it = 0; it < 2; ++it) {
    int row = (tid + it * 256) >> 3;
    aoff[it] = Pbase + (long long)(s0 + row) * FDIM + (tid & 7) * 8;
  }
#pragma unroll
  for (int it = 0; it < 3; ++it) {
    int row = (tid + it * 256) >> 3;
    int t = s0 + row; if (t > S_LEN - 1) t = S_LEN - 1;
    boff[it] = Pbase + (long long)t * FDIM + (tid & 7) * 8;
  }

  const int kbeg = kq * (FDIM / 4), kend = kbeg + FDIM / 4;
  for (int t3 = 0; t3 < 3; ++t3) {
    const hb* Ap = (t3 == 1) ? Plo : Phi;
    const hb* Bp = (t3 == 2) ? Elo : Ehi;
    for (int k0 = kbeg; k0 < kend; k0 += 64) {
#pragma unroll
      for (int it = 0; it < 2; ++it)
        gload16(Ap + aoff[it] + k0, &As[(tid + it * 256) * 8]);
#pragma unroll
      for (int it = 0; it < 3; ++it)
        gload16(Bp + boff[it] + k0, &Bs[(tid + it * 256) * 8]);
      __syncthreads();
#pragma unroll
      for (int ks = 0; ks < 2; ++ks) {
        short8 a[2], bb[3];
#pragma unroll
        for (int mi = 0; mi < 2; ++mi)
          a[mi] = *(const short8*)&As[(wr * 32 + mi * 16 + lrow) * 64 + ks * 32 + lk * 8];
#pragma unroll
        for (int ni = 0; ni < 3; ++ni)
          bb[ni] = *(const short8*)&Bs[(wc * 48 + ni * 16 + lrow) * 64 + ks * 32 + lk * 8];
#pragma unroll
        for (int mi = 0; mi < 2; ++mi)
#pragma unroll
          for (int ni = 0; ni < 3; ++ni)
            acc[mi][ni] = __builtin_amdgcn_mfma_f32_16x16x32_bf16(
                a[mi], bb[ni], acc[mi][ni], 0, 0, 0);
      }
      __syncthreads();
    }
  }

#pragma unroll
  for (int mi = 0; mi < 2; ++mi) {
#pragma unroll
    for (int ni = 0; ni < 3; ++ni) {
#pragma unroll
      for (int q = 0; q < 4; ++q) {
        int i = wr * 32 + mi * 16 + lk * 4 + q;
        int n = wc * 48 + ni * 16 + lrow;
        int d = n - i;
        if (d >= 0 && d < 32) {
          long long off = (((long long)(kq * 2 + b)) * S_LEN + (s0 + i)) * 32 + d;
          partial[off] = acc[mi][ni][q];
        }
      }
    }
  }
}

// sum partials (fixed order), add ssc/esc, clip; -3e38 outside band
__global__ __launch_bounds__(256) void band_reduce(
    const float* __restrict__ partial, const float* __restrict__ ssc,
    const float* __restrict__ esc, float* __restrict__ band)
{
  int idx = blockIdx.x * 256 + threadIdx.x;
  if (idx >= BATCH * S_LEN * 32) return;
  int d = idx & 31;
  int s = (idx >> 5) & (S_LEN - 1);
  int b = idx >> 16;
  int t = s + d;
  float v;
  if (d < MAXSPAN && t < S_LEN) {
    float sum = 0.f;
#pragma unroll
    for (int kq = 0; kq < 4; ++kq)
      sum += partial[(((long long)(kq * 2 + b)) * S_LEN + s) * 32 + d];
    sum += ssc[b * S_LEN + s] + esc[b * S_LEN + t];
    v = fminf(fmaxf(sum, NEGV), -NEGV);
  } else {
    v = -3.0e38f;
  }
  band[idx] = v;
}

// ---------------------------------------------------------------------------
__global__ __launch_bounds__(256) void split_mat(
    const float* __restrict__ src, hb* __restrict__ hi, hb* __restrict__ lo,
    long long n4)
{
  long long i = (long long)blockIdx.x * 256 + threadIdx.x;
  if (i >= n4) return;
  float4 v = ((const float4*)src)[i];
  unsigned short h[4], l[4];
  float vv[4] = {v.x, v.y, v.z, v.w};
#pragma unroll
  for (int j = 0; j < 4; ++j) {
    h[j] = bf_bits(vv[j]);
    l[j] = bf_bits(vv[j] - bf_back(h[j]));
  }
  ((uint2*)hi)[i] = *(uint2*)h;
  ((uint2*)lo)[i] = *(uint2*)l;
}

// split + transpose: src f32 [K][N] -> hiT,loT bf16 [N][K]
__global__ __launch_bounds__(256) void splitT_mat(
    const float* __restrict__ src, hb* __restrict__ hiT, hb* __restrict__ loT,
    int K, int N)
{
  __shared__ float t[32][33];
  int k0 = blockIdx.y * 32, n0 = blockIdx.x * 32;
  int tx = threadIdx.x & 31, ty = threadIdx.x >> 5;
#pragma unroll
  for (int r = 0; r < 4; ++r)
    t[ty + r * 8][tx] = src[(long long)(k0 + ty + r * 8) * N + (n0 + tx)];
  __syncthreads();
#pragma unroll
  for (int r = 0; r < 4; ++r) {
    int n = n0 + ty + r * 8;
    float v = t[tx][ty + r * 8];
    unsigned short h = bf_bits(v);
    unsigned short l = bf_bits(v - bf_back(h));
    hiT[(long long)n * K + k0 + tx] = *reinterpret_cast<hb*>(&h);
    loT[(long long)n * K + k0 + tx] = *reinterpret_cast<hb*>(&l);
  }
}

// ---------------------------------------------------------------------------
// Fused LayerNorm (fp64 stats) + hi/lo bf16 split + cls row-dot (fp64 accum)
// ---------------------------------------------------------------------------
__global__ __launch_bounds__(256) void ln_split_dot(
    const float* __restrict__ src, hb* __restrict__ hi, hb* __restrict__ lo,
    const float* __restrict__ g, const float* __restrict__ be,
    const float* __restrict__ w, const float* __restrict__ wb,
    float* __restrict__ dot_out)
{
  __shared__ float row[FDIM];
  __shared__ double scr[4];
  __shared__ double sh_mu, sh_rstd;
  const long long r = blockIdx.x;
  const float* p = src + r * FDIM;
  const int tid = threadIdx.x;

  double s = 0.0;
#pragma unroll
  for (int pp = 0; pp < 3; ++pp) {
    int c4 = pp * 256 + tid;
    float4 v = *(const float4*)(p + c4 * 4);
    *(float4*)&row[c4 * 4] = v;
    s += (double)v.x + (double)v.y + (double)v.z + (double)v.w;
  }
#pragma unroll
  for (int off = 32; off; off >>= 1) s += __shfl_down(s, off, 64);
  if ((tid & 63) == 0) scr[tid >> 6] = s;
  __syncthreads();
  if (tid == 0) sh_mu = (scr[0] + scr[1] + scr[2] + scr[3]) / FDIM;
  __syncthreads();
  double mu = sh_mu;
  double vs = 0.0;
#pragma unroll
  for (int pp = 0; pp < 12; ++pp) {
    double d = (double)row[pp * 256 + tid] - mu;
    vs += d * d;
  }
#pragma unroll
  for (int off = 32; off; off >>= 1) vs += __shfl_down(vs, off, 64);
  __syncthreads();
  if ((tid & 63) == 0) scr[tid >> 6] = vs;
  __syncthreads();
  if (tid == 0)
    sh_rstd = 1.0 / sqrt((scr[0] + scr[1] + scr[2] + scr[3]) / FDIM + 1e-5);
  __syncthreads();
  double rstd = sh_rstd;

  double dot = 0.0;
#pragma unroll
  for (int pp = 0; pp < 3; ++pp) {
    int c4 = pp * 256 + tid;
    float4 gv = *(const float4*)(g + c4 * 4);
    float4 bv = *(const float4*)(be + c4 * 4);
    float4 wv = *(const float4*)(w + c4 * 4);
    float xv[4];
    *(float4*)xv = *(const float4*)&row[c4 * 4];
    unsigned short hh[4], ll[4];
    float gg[4] = {gv.x, gv.y, gv.z, gv.w};
    float bb[4] = {bv.x, bv.y, bv.z, bv.w};
    float ww[4] = {wv.x, wv.y, wv.z, wv.w};
#pragma unroll
    for (int j = 0; j < 4; ++j) {
      float val = (float)(((double)xv[j] - mu) * rstd * (double)gg[j] + (double)bb[j]);
      dot += (double)val * (double)ww[j];
      hh[j] = bf_bits(val);
      ll[j] = bf_bits(val - bf_back(hh[j]));
    }
    *(uint2*)(hi + r * FDIM + c4 * 4) = *(uint2*)hh;
    *(uint2*)(lo + r * FDIM + c4 * 4) = *(uint2*)ll;
  }
#pragma unroll
  for (int off = 32; off; off >>= 1) dot += __shfl_down(dot, off, 64);
  __syncthreads();
  if ((tid & 63) == 0) scr[tid >> 6] = dot;
  __syncthreads();
  if (tid == 0)
    dot_out[r] = (float)(scr[0] + scr[1] + scr[2] + scr[3] + (double)wb[0]);
}

// LayerNorm f32 src -> bf16 dst, z-batched pair (phase-2)
__global__ __launch_bounds__(256) void ln_rows_bf2(
    const float* __restrict__ src0, const float* __restrict__ src1,
    hb* __restrict__ dst0, hb* __restrict__ dst1,
    const float* __restrict__ g0, const float* __restrict__ g1,
    const float* __restrict__ be0, const float* __restrict__ be1,
    int n, long long lds_, long long ldd)
{
  const int sel = blockIdx.y;
  long long r = blockIdx.x;
  const float* p = (sel ? src1 : src0) + r * lds_;
  hb* d = (sel ? dst1 : dst0) + r * ldd;
  const float* g = sel ? g1 : g0;
  const float* be = sel ? be1 : be0;
  __shared__ double scratch[4];
  __shared__ double sh_mu, sh_rstd;
  double s = 0.0;
  for (int c = threadIdx.x; c < n; c += 256) s += (double)p[c];
#pragma unroll
  for (int off = 32; off; off >>= 1) s += __shfl_down(s, off, 64);
  if ((threadIdx.x & 63) == 0) scratch[threadIdx.x >> 6] = s;
  __syncthreads();
  if (threadIdx.x == 0) sh_mu = (scratch[0] + scratch[1] + scratch[2] + scratch[3]) / n;
  __syncthreads();
  double mu = sh_mu;
  double vs = 0.0;
  for (int c = threadIdx.x; c < n; c += 256) { double dd = (double)p[c] - mu; vs += dd * dd; }
#pragma unroll
  for (int off = 32; off; off >>= 1) vs += __shfl_down(vs, off, 64);
  __syncthreads();
  if ((threadIdx.x & 63) == 0) scratch[threadIdx.x >> 6] = vs;
  __syncthreads();
  if (threadIdx.x == 0)
    sh_rstd = 1.0 / sqrt((scratch[0] + scratch[1] + scratch[2] + scratch[3]) / n + 1e-5);
  __syncthreads();
  double rstd = sh_rstd;
  for (int c = threadIdx.x; c < n; c += 256)
    d[c] = __float2bfloat16(
        (float)(((double)p[c] - mu) * rstd * (double)g[c] + (double)be[c]));
}

// ---------------------------------------------------------------------------
// Top-k selection (radix on monotone float keys) + index sort, 1 block/batch
// ---------------------------------------------------------------------------
__device__ __forceinline__ unsigned f2k(float f) {
  unsigned u = __float_as_uint(f);
  return (u & 0x80000000u) ? ~u : (u | 0x80000000u);
}

__device__ void bitonic1024(int* a) {
  const int tid = threadIdx.x;
  for (int sz = 2; sz <= 1024; sz <<= 1) {
    for (int st = sz >> 1; st > 0; st >>= 1) {
      __syncthreads();
      int j = tid ^ st;
      if (j > tid) {
        int x = a[tid], y = a[j];
        bool asc = (tid & sz) == 0;
        if ((x > y) == asc) { a[tid] = y; a[j] = x; }
      }
    }
  }
  __syncthreads();
}

__global__ __launch_bounds__(1024) void select_sort(
    const float* __restrict__ band, const int* __restrict__ masks,
    int* __restrict__ sidx, int* __restrict__ starts, int* __restrict__ ends,
    float* __restrict__ tms, int* __restrict__ kvals)
{
  const int b = blockIdx.x;
  const int tid = threadIdx.x;
  __shared__ int hist[256];
  __shared__ int sel[1024];
  __shared__ int eq[1024];
  __shared__ int sred[16];
  __shared__ int cvar[4];
  __shared__ int cnt_gt, cnt_eq;

  int msum = 0;
  for (int i = tid; i < S_LEN; i += 1024) msum += masks[b * S_LEN + i];
#pragma unroll
  for (int off = 32; off; off >>= 1) msum += __shfl_down(msum, off, 64);
  if ((tid & 63) == 0) sred[tid >> 6] = msum;
  __syncthreads();
  if (tid == 0) {
    int t = 0;
    for (int w = 0; w < 16; ++w) t += sred[w];
    cvar[2] = t;
  }
  __syncthreads();
  int kv = (int)((float)cvar[2] * 0.4f);
  if (kv > MAXK) kv = MAXK;
  if (kv < 0) kv = 0;

  const int NC = S_LEN * MAXSPAN;
  unsigned prefix = 0u;
  int remaining = kv;

  if (kv > 0) {
    for (int byte = 3; byte >= 0; --byte) {
      if (tid < 256) hist[tid] = 0;
      __syncthreads();
      for (int i = tid; i < NC; i += 1024) {
        int s = i / MAXSPAN;
        int d = i - s * MAXSPAN;
        float v = band[((long long)(b * S_LEN + s)) * 32 + d];
        unsigned key = f2k(v);
        bool match = (byte == 3) ||
            ((key >> ((byte + 1) * 8)) == (prefix >> ((byte + 1) * 8)));
        if (match) atomicAdd(&hist[(key >> (byte * 8)) & 255], 1);
      }
      __syncthreads();
      if (tid == 0) {
        int cum = 0, chosen = 255;
        for (int v = 255; v >= 0; --v) {
          int h = hist[v];
          if (cum + h >= remaining) { chosen = v; cvar[0] = remaining - cum; break; }
          cum += h;
        }
        cvar[1] = chosen;
      }
      __syncthreads();
      remaining = cvar[0];
      prefix |= ((unsigned)cvar[1]) << (byte * 8);
      __syncthreads();
    }
    if (tid == 0) { cnt_gt = 0; cnt_eq = 0; }
    __syncthreads();
    for (int i = tid; i < NC; i += 1024) {
      int s = i / MAXSPAN;
      int d = i - s * MAXSPAN;
      float v = band[((long long)(b * S_LEN + s)) * 32 + d];
      unsigned key = f2k(v);
      int flat = s * S_LEN + s + d;
      if (key > prefix) {
        int p = atomicAdd(&cnt_gt, 1);
        if (p < MAXK) sel[p] = flat;
      } else if (key == prefix) {
        int p = atomicAdd(&cnt_eq, 1);
        if (p < 1024) eq[p] = flat;
      }
    }
    __syncthreads();
    int ngt = cnt_gt;
    int neq = cnt_eq; if (neq > 1024) neq = 1024;
    if (tid >= neq) eq[tid] = 0x7FFFFFFF;
    __syncthreads();
    bitonic1024(eq);
    int need = kv - ngt;
    if (tid < need) sel[ngt + tid] = eq[tid];
    __syncthreads();
  }
  if (tid >= kv && tid < MAXK) sel[tid] = S_LEN * S_LEN - 1;
  if (tid >= MAXK) sel[tid] = 0x7FFFFFFF;
  __syncthreads();
  bitonic1024(sel);
  if (tid < MAXK) {
    int idx = sel[tid];
    int s = idx >> 11;
    int t = idx & (S_LEN - 1);
    sidx[b * MAXK + tid] = idx;
    starts[b * MAXK + tid] = s;
    ends[b * MAXK + tid] = t;
    tms[b * MAXK + tid] = band[((long long)(b * S_LEN + s)) * 32 + (t - s)];
  }
  if (tid == 0) kvals[b] = kv;
}

// y-batched gather pair: y=0 rows0->dst0, y=1 rows1->dst1 (H = 1024)
__global__ __launch_bounds__(256) void gather_bf2(
    const float* __restrict__ src,
    const int* __restrict__ rows0, const int* __restrict__ rows1,
    hb* __restrict__ dst0, hb* __restrict__ dst1)
{
  int g = blockIdx.x;
  int b = g / MAXK;
  const int* rows = blockIdx.y ? rows1 : rows0;
  hb* dst = blockIdx.y ? dst1 : dst0;
  int r = rows[g];
  const float4* s4 = (const float4*)(src + ((long long)(b * S_LEN + r)) * HDIM);
  hb* d = dst + (long long)g * HDIM;
  float4 v = s4[threadIdx.x];
  d[threadIdx.x * 4 + 0] = __float2bfloat16(v.x);
  d[threadIdx.x * 4 + 1] = __float2bfloat16(v.y);
  d[threadIdx.x * 4 + 2] = __float2bfloat16(v.z);
  d[threadIdx.x * 4 + 3] = __float2bfloat16(v.w);
}

// transpose+convert pair (z=2): dst[n][k] (bf16, row stride ldd) = src[k][n]
__global__ __launch_bounds__(256) void conv_t2(
    const float* __restrict__ src0, const float* __restrict__ src1,
    hb* __restrict__ dst0, hb* __restrict__ dst1,
    int K, int N, int ldd)
{
  __shared__ float t[32][33];
  const float* src = blockIdx.z ? src1 : src0;
  hb* dst = blockIdx.z ? dst1 : dst0;
  int k0 = blockIdx.y * 32, n0 = blockIdx.x * 32;
  int tx = threadIdx.x & 31, ty = threadIdx.x >> 5;
#pragma unroll
  for (int r = 0; r < 4; ++r)
    t[ty + r * 8][tx] = src[(long long)(k0 + ty + r * 8) * N + (n0 + tx)];
  __syncthreads();
#pragma unroll
  for (int r = 0; r < 4; ++r) {
    int n = n0 + ty + r * 8;
    dst[(long long)n * ldd + k0 + tx] = __float2bfloat16(t[tx][ty + r * 8]);
  }
}

// transpose+convert 4-way (a_* weights, K=N=FDIM): z in 0..3 ->
// dst = (z<2 ? d01 : d23), koff = (z&1)*FDIM, ldd = 2*FDIM
__global__ __launch_bounds__(256) void conv_t4(
    const float* __restrict__ s0, const float* __restrict__ s1,
    const float* __restrict__ s2, const float* __restrict__ s3,
    hb* __restrict__ d01, hb* __restrict__ d23)
{
  __shared__ float t[32][33];
  const int z = blockIdx.z;
  const float* src = (z == 0) ? s0 : (z == 1) ? s1 : (z == 2) ? s2 : s3;
  hb* dst = (z < 2) ? d01 : d23;
  const int koff = (z & 1) * FDIM;
  int k0 = blockIdx.y * 32, n0 = blockIdx.x * 32;
  int tx = threadIdx.x & 31, ty = threadIdx.x >> 5;
#pragma unroll
  for (int r = 0; r < 4; ++r)
    t[ty + r * 8][tx] = src[(long long)(k0 + ty + r * 8) * FDIM + (n0 + tx)];
  __syncthreads();
#pragma unroll
  for (int r = 0; r < 4; ++r) {
    int n = n0 + ty + r * 8;
    dst[(long long)n * (2 * FDIM) + koff + k0 + tx] =
        __float2bfloat16(t[tx][ty + r * 8]);
  }
}

// c[0:n] = a0+b0 ; c[n:2n] = a1+b1   (c spans contiguous biasq1|biasq2)
__global__ __launch_bounds__(256) void add2cat(
    const float* __restrict__ a0, const float* __restrict__ b0,
    const float* __restrict__ a1, const float* __restrict__ b1,
    float* __restrict__ c, int n)
{
  int i = blockIdx.x * 256 + threadIdx.x;
  if (i < n) c[i] = a0[i] + b0[i];
  else if (i < 2 * n) c[i] = a1[i - n] + b1[i - n];
}

// out[b,i,j] assembly: sum 4 coref K-slices + pair + anaphora mask, zero last col
__global__ __launch_bounds__(256) void final_assemble(
    const float* __restrict__ coref4, const float* __restrict__ tms,
    const int* __restrict__ kvals, float* __restrict__ out)
{
  const long long SL = (long long)MAXK * MAXK;   // slice stride
  int g = blockIdx.x;                   // b*MAXK + i
  int b = g / MAXK;
  int i = g - b * MAXK;
  int kv = kvals[b];
  float ti = tms[g];
  const float* crow = coref4 + (long long)(b * 4) * SL + (long long)i * MAXK;
  float* orow = out + (long long)b * MAXK * (MAXK + 1) + (long long)i * (MAXK + 1);
  for (int j = threadIdx.x; j < MAXK + 1; j += 256) {
    float v;
    if (j == MAXK) v = 0.f;
    else {
      float c = ((crow[j] + crow[j + SL]) + (crow[j + 2 * SL] + crow[j + 3 * SL]));
      v = ti + tms[b * MAXK + j] + c;
      if (!((j < i) && (i < kv))) v += NEGV;
      v = fminf(fmaxf(v, NEGV), -NEGV);
    }
    orow[j] = v;
  }
}

// ---------------------------------------------------------------------------
static inline void launch1(const hb* A, const hb* B,
    const float* bias, const float* bias2, void* C,
    int M, int N, int K, int lda, int ldb, int ldc,
    long long sA, long long sB, long long sC,
    int act, int out_mode, int zcount, int kspl, hipStream_t stream)
{
  dim3 grid((N + 127) / 128, (M + 127) / 128, zcount);
  gemm_fast1<<<grid, 256, 0, stream>>>(A, B, bias, bias2, C, M, N, K,
                                       lda, ldb, ldc, sA, sB, sC,
                                       act, out_mode, kspl);
}

static inline void launch3(const hb* Ah, const hb* Al, const hb* Bh, const hb* Bl,
    const float* bias, void* C, void* C2, int M, int N, int K,
    int lda, int ldb, int ldc, int act, int out_mode, hipStream_t stream)
{
  dim3 grid((N + 127) / 128, (M + 127) / 128, 1);
  gemm_fast3<<<grid, 256, 0, stream>>>(Ah, Al, Bh, Bl, bias, C, C2,
                                       M, N, K, lda, ldb, ldc, act, out_mode);
}

extern "C" void kernel_launch(void* const* d_in, const int* in_sizes, int n_in,
                              void* d_out, int out_size, void* d_ws, size_t ws_size,
                              hipStream_t stream) {
  const float* input_emb = (const float*)d_in[0];
  const int*   input_masks = (const int*)d_in[1];
  const float* sm_W = (const float*)d_in[2];
  const float* sm_b = (const float*)d_in[3];
  const float* sm_g = (const float*)d_in[4];
  const float* sm_be = (const float*)d_in[5];
  const float* em_W = (const float*)d_in[6];
  const float* em_b = (const float*)d_in[7];
  const float* em_g = (const float*)d_in[8];
  const float* em_be = (const float*)d_in[9];
  const float* sc_W = (const float*)d_in[10];
  const float* sc_b = (const float*)d_in[11];
  const float* sc_g = (const float*)d_in[12];
  const float* sc_be = (const float*)d_in[13];
  const float* ec_W = (const float*)d_in[14];
  const float* ec_b = (const float*)d_in[15];
  const float* ec_g = (const float*)d_in[16];
  const float* ec_be = (const float*)d_in[17];
  const float* cls_s_W = (const float*)d_in[18];
  const float* cls_s_b = (const float*)d_in[19];
  const float* cls_e_W = (const float*)d_in[20];
  const float* cls_e_b = (const float*)d_in[21];
  const float* s2e_W = (const float*)d_in[22];
  const float* s2e_b = (const float*)d_in[23];
  const float* a_ss_W = (const float*)d_in[24];
  const float* a_ss_b = (const float*)d_in[25];
  const float* a_ee_W = (const float*)d_in[26];
  const float* a_ee_b = (const float*)d_in[27];
  const float* a_se_W = (const float*)d_in[28];
  const float* a_se_b = (const float*)d_in[29];
  const float* a_es_W = (const float*)d_in[30];
  const float* a_es_b = (const float*)d_in[31];
  float* out = (float*)d_out;

  const int NROW = BATCH * S_LEN;           // 4096
  const int MROW = BATCH * MAXK;            // 1638
  const long long SZ_BIG = (long long)NROW * FDIM * 4;      // 50331648

  char* ws = (char*)d_ws;
  // ---- phase-1 regions (schedule in launch order) ----
  float* smF    = (float*)(ws);                     // sm f32, dead after LN
  hb* sm_hi     = (hb*)(ws + 50331648LL);
  hb* sm_lo     = (hb*)(ws + 75497472LL);
  hb* emb_hi    = (hb*)(ws + 100663296LL);
  hb* emb_lo    = (hb*)(ws + 109051904LL);
  hb* w1_hiT    = (hb*)(ws + 117440512LL);
  hb* w1_loT    = (hb*)(ws + 123731968LL);
  hb* s2e_hiT   = (hb*)(ws);                        // after smF dead
  hb* s2e_loT   = (hb*)(ws + 18874368LL);
  hb* proj_hi   = (hb*)(ws + 100663296LL);          // after emb/w1 dead
  hb* proj_lo   = (hb*)(ws + 125829120LL);
  hb* emb2_hi   = (hb*)(ws);                        // after s2eT dead
  hb* emb2_lo   = (hb*)(ws + 8388608LL);
  hb* w2_hiT    = (hb*)(ws + 16777216LL);
  hb* w2_loT    = (hb*)(ws + 23068672LL);
  float* emF    = (float*)(ws + 50331648LL);        // after sm splits dead
  hb* em_hi     = (hb*)(ws);                        // after emb2/w2 dead
  hb* em_lo     = (hb*)(ws + 25165824LL);
  float* partial = (float*)(ws + 50331648LL);       // after emF dead, 2 MB
  // ---- phase-2 overlay ----
  hb* tkcat = (hb*)(ws);                            // [1638][6144]
  hb* qcat  = (hb*)(ws + 20127744LL);
  float* mlp_s = (float*)(ws + 40255488LL);
  float* mlp_e = (float*)(ws + 60383232LL);
  hb* Xs_bf = (hb*)(ws + 80510976LL);
  hb* Xe_bf = (hb*)(ws + 83865600LL);
  hb* scWt  = (hb*)(ws + 87220224LL);
  hb* ecWt  = (hb*)(ws + 93511680LL);
  float* coref4 = (float*)(ws + 99803136LL);        // [2][4][819][819] f32, 21.5 MB
  hb* Wq1t = (hb*)(ws + 40255488LL);                // [3072][6144]
  hb* Wq2t = (hb*)(ws + 78004224LL);                // contiguous after Wq1t
  // ---- persistent tail ----
  const long long P = 3 * SZ_BIG;                   // 150994944
  float* band = (float*)(ws + P);
  float* ssc  = (float*)(ws + P + 524288);
  float* esc  = (float*)(ws + P + 540672);
  int* sidx   = (int*)(ws + P + 557056);
  int* starts = (int*)(ws + P + 565248);
  int* ends   = (int*)(ws + P + 573440);
  float* tms  = (float*)(ws + P + 581632);
  int* kvals  = (int*)(ws + P + 589824);
  float* biasq1 = (float*)(ws + P + 590080);        // [3072]
  float* biasq2 = (float*)(ws + P + 602368);        // contiguous -> [6144] cat
  if (ws_size < (size_t)(P + 614656)) return;

  const long long n4_emb = (long long)NROW * HDIM / 4;

  // ---- phase 1: selection-critical chain ----
  split_mat<<<(int)((n4_emb + 255) / 256), 256, 0, stream>>>(input_emb, emb_hi, emb_lo, n4_emb);
  splitT_mat<<<dim3(FDIM / 32, HDIM / 32), 256, 0, stream>>>(sm_W, w1_hiT, w1_loT, HDIM, FDIM);
  launch3(emb_hi, emb_lo, w1_hiT, w1_loT, sm_b, smF, nullptr,
          NROW, FDIM, HDIM, HDIM, HDIM, FDIM, 1, 0, stream);
  ln_split_dot<<<NROW, 256, 0, stream>>>(smF, sm_hi, sm_lo, sm_g, sm_be,
                                         cls_s_W, cls_s_b, ssc);
  splitT_mat<<<dim3(FDIM / 32, FDIM / 32), 256, 0, stream>>>(s2e_W, s2e_hiT, s2e_loT, FDIM, FDIM);
  launch3(sm_hi, sm_lo, s2e_hiT, s2e_loT, s2e_b, proj_hi, proj_lo,
          NROW, FDIM, FDIM, FDIM, FDIM, FDIM, 0, 2, stream);
  split_mat<<<(int)((n4_emb + 255) / 256), 256, 0, stream>>>(input_emb, emb2_hi, emb2_lo, n4_emb);
  splitT_mat<<<dim3(FDIM / 32, HDIM / 32), 256, 0, stream>>>(em_W, w2_hiT, w2_loT, HDIM, FDIM);
  launch3(emb2_hi, emb2_lo, w2_hiT, w2_loT, em_b, emF, nullptr,
          NROW, FDIM, HDIM, HDIM, HDIM, FDIM, 1, 0, stream);
  ln_split_dot<<<NROW, 256, 0, stream>>>(emF, em_hi, em_lo, em_g, em_be,
                                         cls_e_W, cls_e_b, esc);
  bandmm<<<dim3(S_LEN / 64, 4, BATCH), 256, 0, stream>>>(proj_hi, proj_lo, em_hi, em_lo, partial);
  band_reduce<<<(BATCH * S_LEN * 32) / 256, 256, 0, stream>>>(partial, ssc, esc, band);
  select_sort<<<BATCH, 1024, 0, stream>>>(band, input_masks, sidx, starts, ends, tms, kvals);

  // ---- phase 2: gathered coref reps, bf16 MFMA (batched launches) ----
  gather_bf2<<<dim3(MROW, 2), 256, 0, stream>>>(input_emb, starts, ends, Xs_bf, Xe_bf);

  conv_t2<<<dim3(FDIM / 32, HDIM / 32, 2), 256, 0, stream>>>(
      sc_W, ec_W, scWt, ecWt, HDIM, FDIM, HDIM);

  // batched mlp_s/mlp_e: z=2, contiguous operand strides, per-z bias
  launch1(Xs_bf, scWt, sc_b, ec_b, mlp_s, MROW, FDIM, HDIM, HDIM, HDIM, FDIM,
          (long long)MROW * HDIM, (long long)FDIM * HDIM, (long long)MROW * FDIM,
          1, 0, 2, 1, stream);

  ln_rows_bf2<<<dim3(MROW, 2), 256, 0, stream>>>(
      mlp_s, mlp_e, tkcat, tkcat + FDIM, sc_g, ec_g, sc_be, ec_be,
      FDIM, FDIM, 2 * FDIM);

  conv_t4<<<dim3(FDIM / 32, FDIM / 32, 4), 256, 0, stream>>>(
      a_ss_W, a_es_W, a_se_W, a_ee_W, Wq1t, Wq2t);
  add2cat<<<(2 * FDIM) / 256, 256, 0, stream>>>(
      a_ss_b, a_es_b, a_se_b, a_ee_b, biasq1, FDIM);

  // fused qcat: N = 6144 over contiguous [Wq1t; Wq2t] and [biasq1|biasq2]
  launch1(tkcat, Wq1t, biasq1, nullptr, qcat, MROW, 2 * FDIM, 2 * FDIM,
          2 * FDIM, 2 * FDIM, 2 * FDIM, 0, 0, 0, 0, 1, 1, 1, stream);

  // coref: split-K x4 (K=1536/slice), batched z = b*4 + ks
  launch1(qcat, tkcat, nullptr, nullptr, coref4, MAXK, MAXK, 1536,
          2 * FDIM, 2 * FDIM, MAXK,
          (long long)MAXK * 2 * FDIM, (long long)MAXK * 2 * FDIM,
          (long long)MAXK * MAXK, 0, 0, BATCH * 4, 4, stream);

  final_assemble<<<MROW, 256, 0, stream>>>(coref4, tms, kvals, out);
}

// Round 5
// 1206.504 us; speedup vs baseline: 1.1665x; 1.0309x over previous
//
#include <hip/hip_runtime.h>
#include <hip/hip_bf16.h>
#include <math.h>

#define S_LEN 2048
#define BATCH 2
#define HDIM 1024
#define FDIM 3072
#define MAXK 819
#define MAXSPAN 30
#define NEGV -10000.0f

typedef __attribute__((ext_vector_type(8))) short short8;
typedef __attribute__((ext_vector_type(4))) float f32x4;
typedef __hip_bfloat16 hb;

__device__ __forceinline__ float gelu_f(float x) {
  return 0.5f * x * (1.0f + erff(x * 0.70710678118654752440f));
}

__device__ __forceinline__ unsigned short bf_bits(float x) {
  hb b = __float2bfloat16(x);
  return *reinterpret_cast<unsigned short*>(&b);
}
__device__ __forceinline__ float bf_back(unsigned short u) {
  hb b = *reinterpret_cast<hb*>(&u);
  return __bfloat162float(b);
}

__device__ __forceinline__ void gload16(const void* g, void* l) {
  __builtin_amdgcn_global_load_lds(
      (const __attribute__((address_space(1))) void*)g,
      (__attribute__((address_space(3))) void*)l, 16, 0, 0);
}

// ---------------------------------------------------------------------------
// bf16 MFMA GEMM, single-term, BK=128 (128 MFMA per barrier-pair).
// C[M,N] = act(A[M,K] @ B[N,K]^T + bias).  K multiple of 128.
// z-batching: blockIdx.z = zb*kspl + zk; operands at zb*sA/sB, k-slice zk,
// C slice at blockIdx.z * sC.  bias2 (if non-null) replaces bias for zb>=1.
// NOTE: XCD-chunked blockIdx remap was tried (r1/r2) and REGRESSED here:
// inputs are L3-resident and kernel is not HBM-bound; chunking de-correlates
// the XCDs' B-panel streams (FETCH 240->326 MB). Keep default dispatch order.
// ---------------------------------------------------------------------------
__global__ __launch_bounds__(256) void gemm_fast1(
    const hb* __restrict__ A, const hb* __restrict__ B,
    const float* __restrict__ bias, const float* __restrict__ bias2,
    void* __restrict__ Cv,
    int M, int N, int K, int lda, int ldb, int ldc,
    long long sA, long long sB, long long sC,
    int act, int out_mode, int kspl)
{
  const int zb = blockIdx.z / kspl, zk = blockIdx.z - zb * kspl;
  A += (long long)zb * sA + (long long)zk * K;
  B += (long long)zb * sB + (long long)zk * K;
  const long long cbase = (long long)blockIdx.z * sC;
  const float* bp = (bias2 && zb) ? bias2 : bias;
  const int bm = blockIdx.y * 128, bn = blockIdx.x * 128;
  const int tid = threadIdx.x;
  const int lane = tid & 63;
  const int wv = tid >> 6, wr = wv >> 1, wc = wv & 1;
  const int lrow = lane & 15, lk = lane >> 4;
  __shared__ __align__(16) hb As[128 * 128];
  __shared__ __align__(16) hb Bs[128 * 128];

  const int srow = tid >> 4;          // 0..15
  const int sc8 = tid & 15;           // 16 slots of 8 bf16
  const int sslot = (sc8 - srow) & 15;  // inverse swizzle on global source

  f32x4 acc[4][4];
#pragma unroll
  for (int mi = 0; mi < 4; ++mi)
#pragma unroll
    for (int ni = 0; ni < 4; ++ni) acc[mi][ni] = (f32x4){0.f, 0.f, 0.f, 0.f};

  long long aoff[8], boff[8];
#pragma unroll
  for (int it = 0; it < 8; ++it) {
    int gm = bm + srow + it * 16; if (gm > M - 1) gm = M - 1;
    int gn = bn + srow + it * 16; if (gn > N - 1) gn = N - 1;
    aoff[it] = (long long)gm * lda + sslot * 8;
    boff[it] = (long long)gn * ldb + sslot * 8;
  }

  for (int k0 = 0; k0 < K; k0 += 128) {
#pragma unroll
    for (int it = 0; it < 8; ++it)
      gload16(A + aoff[it] + k0, &As[(tid + it * 256) * 8]);
#pragma unroll
    for (int it = 0; it < 8; ++it)
      gload16(B + boff[it] + k0, &Bs[(tid + it * 256) * 8]);
    __syncthreads();
#pragma unroll
    for (int ks = 0; ks < 4; ++ks) {
      const int sa = ((ks * 4 + lk + lrow) & 15) * 8;   // swizzled read slot
      short8 a[4], b[4];
#pragma unroll
      for (int mi = 0; mi < 4; ++mi)
        a[mi] = *(const short8*)&As[(wr * 64 + mi * 16 + lrow) * 128 + sa];
#pragma unroll
      for (int ni = 0; ni < 4; ++ni)
        b[ni] = *(const short8*)&Bs[(wc * 64 + ni * 16 + lrow) * 128 + sa];
#pragma unroll
      for (int mi = 0; mi < 4; ++mi)
#pragma unroll
        for (int ni = 0; ni < 4; ++ni)
          acc[mi][ni] = __builtin_amdgcn_mfma_f32_16x16x32_bf16(
              a[mi], b[ni], acc[mi][ni], 0, 0, 0);
    }
    __syncthreads();
  }

  float* Cf = (float*)Cv;
  hb* Cb = (hb*)Cv;
#pragma unroll
  for (int mi = 0; mi < 4; ++mi) {
#pragma unroll
    for (int ni = 0; ni < 4; ++ni) {
#pragma unroll
      for (int q = 0; q < 4; ++q) {
        int gm = bm + wr * 64 + mi * 16 + lk * 4 + q;
        int gn = bn + wc * 64 + ni * 16 + lrow;
        if (gm < M && gn < N) {
          float v = acc[mi][ni][q];
          if (bp)   v += bp[gn];
          if (act)  v = gelu_f(v);
          long long off = cbase + (long long)gm * ldc + gn;
          if (out_mode == 1) Cb[off] = __float2bfloat16(v);
          else               Cf[off] = v;
        }
      }
    }
  }
}

// ---------------------------------------------------------------------------
// Fused split-bf16 3-term GEMM (fp32-equivalent): stages A_hi,A_lo,B_hi,B_lo
// once per K-tile (64KB LDS), 96 MFMAs per K-tile (hh + lh + hl). BK=64.
// out_mode: 0 = f32, 2 = split hi/lo bf16.
// ---------------------------------------------------------------------------
__global__ __launch_bounds__(256) void gemm_fast3(
    const hb* __restrict__ Ah, const hb* __restrict__ Al,
    const hb* __restrict__ Bh, const hb* __restrict__ Bl,
    const float* __restrict__ bias, void* __restrict__ Cv, void* __restrict__ Cv2,
    int M, int N, int K, int lda, int ldb, int ldc, int act, int out_mode)
{
  const int bm = blockIdx.y * 128, bn = blockIdx.x * 128;
  const int tid = threadIdx.x;
  const int lane = tid & 63;
  const int wv = tid >> 6, wr = wv >> 1, wc = wv & 1;
  const int lrow = lane & 15, lk = lane >> 4;
  __shared__ __align__(16) hb AsH[128 * 64];
  __shared__ __align__(16) hb AsL[128 * 64];
  __shared__ __align__(16) hb BsH[128 * 64];
  __shared__ __align__(16) hb BsL[128 * 64];

  const int srow = tid >> 3;
  const int sc8 = tid & 7;
  const int sslot = (sc8 - srow) & 7;

  f32x4 acc[4][4];
#pragma unroll
  for (int mi = 0; mi < 4; ++mi)
#pragma unroll
    for (int ni = 0; ni < 4; ++ni) acc[mi][ni] = (f32x4){0.f, 0.f, 0.f, 0.f};

  long long aoff[4], boff[4];
#pragma unroll
  for (int it = 0; it < 4; ++it) {
    int gm = bm + srow + it * 32; if (gm > M - 1) gm = M - 1;
    int gn = bn + srow + it * 32; if (gn > N - 1) gn = N - 1;
    aoff[it] = (long long)gm * lda + sslot * 8;
    boff[it] = (long long)gn * ldb + sslot * 8;
  }

  for (int k0 = 0; k0 < K; k0 += 64) {
#pragma unroll
    for (int it = 0; it < 4; ++it) {
      gload16(Ah + aoff[it] + k0, &AsH[(tid + it * 256) * 8]);
      gload16(Al + aoff[it] + k0, &AsL[(tid + it * 256) * 8]);
      gload16(Bh + boff[it] + k0, &BsH[(tid + it * 256) * 8]);
      gload16(Bl + boff[it] + k0, &BsL[(tid + it * 256) * 8]);
    }
    __syncthreads();
#pragma unroll
    for (int ks = 0; ks < 2; ++ks) {
      const int sa = ((ks * 4 + lk + lrow) & 7) * 8;
      short8 aH[4], aL[4], bH[4], bL[4];
#pragma unroll
      for (int mi = 0; mi < 4; ++mi) {
        int r = (wr * 64 + mi * 16 + lrow) * 64 + sa;
        aH[mi] = *(const short8*)&AsH[r];
        aL[mi] = *(const short8*)&AsL[r];
      }
#pragma unroll
      for (int ni = 0; ni < 4; ++ni) {
        int r = (wc * 64 + ni * 16 + lrow) * 64 + sa;
        bH[ni] = *(const short8*)&BsH[r];
        bL[ni] = *(const short8*)&BsL[r];
      }
#pragma unroll
      for (int mi = 0; mi < 4; ++mi)
#pragma unroll
        for (int ni = 0; ni < 4; ++ni) {
          acc[mi][ni] = __builtin_amdgcn_mfma_f32_16x16x32_bf16(
              aH[mi], bH[ni], acc[mi][ni], 0, 0, 0);
          acc[mi][ni] = __builtin_amdgcn_mfma_f32_16x16x32_bf16(
              aL[mi], bH[ni], acc[mi][ni], 0, 0, 0);
          acc[mi][ni] = __builtin_amdgcn_mfma_f32_16x16x32_bf16(
              aH[mi], bL[ni], acc[mi][ni], 0, 0, 0);
        }
    }
    __syncthreads();
  }

  float* Cf = (float*)Cv;
  hb* Cb = (hb*)Cv;
  hb* Cb2 = (hb*)Cv2;
#pragma unroll
  for (int mi = 0; mi < 4; ++mi) {
#pragma unroll
    for (int ni = 0; ni < 4; ++ni) {
#pragma unroll
      for (int q = 0; q < 4; ++q) {
        int gm = bm + wr * 64 + mi * 16 + lk * 4 + q;
        int gn = bn + wc * 64 + ni * 16 + lrow;
        if (gm < M && gn < N) {
          float v = acc[mi][ni][q];
          if (bias) v += bias[gn];
          if (act)  v = gelu_f(v);
          long long off = (long long)gm * ldc + gn;
          if (out_mode == 2) {
            unsigned short h = bf_bits(v);
            unsigned short l = bf_bits(v - bf_back(h));
            Cb[off] = *reinterpret_cast<hb*>(&h);
            Cb2[off] = *reinterpret_cast<hb*>(&l);
          } else {
            Cf[off] = v;
          }
        }
      }
    }
  }
}

// ---------------------------------------------------------------------------
// Banded MFMA: partial[kq][b][s][d] = proj[s].em[s+d] over K-quarter (3-term)
// ---------------------------------------------------------------------------
__global__ __launch_bounds__(256) void bandmm(
    const hb* __restrict__ Phi, const hb* __restrict__ Plo,
    const hb* __restrict__ Ehi, const hb* __restrict__ Elo,
    float* __restrict__ partial)
{
  const int s0 = blockIdx.x * 64;
  const int kq = blockIdx.y;
  const int b = blockIdx.z;
  const int tid = threadIdx.x;
  const int lane = tid & 63;
  const int wv = tid >> 6, wr = wv >> 1, wc = wv & 1;
  const int lrow = lane & 15, lk = lane >> 4;
  __shared__ __align__(16) hb As[64 * 64];
  __shared__ __align__(16) hb Bs[96 * 64];

  f32x4 acc[2][3];
#pragma unroll
  for (int mi = 0; mi < 2; ++mi)
#pragma unroll
    for (int ni = 0; ni < 3; ++ni) acc[mi][ni] = (f32x4){0.f, 0.f, 0.f, 0.f};

  const long long Pbase = (long long)(b * S_LEN) * FDIM;
  long long aoff[2], boff[3];
#pragma unroll
  for (int it = 0; it < 2; ++it) {
    int row = (tid + it * 256) >> 3;
    aoff[it] = Pbase + (long long)(s0 + row) * FDIM + (tid & 7) * 8;
  }
#pragma unroll
  for (int it = 0; it < 3; ++it) {
    int row = (tid + it * 256) >> 3;
    int t = s0 + row; if (t > S_LEN - 1) t = S_LEN - 1;
    boff[it] = Pbase + (long long)t * FDIM + (tid & 7) * 8;
  }

  const int kbeg = kq * (FDIM / 4), kend = kbeg + FDIM / 4;
  for (int t3 = 0; t3 < 3; ++t3) {
    const hb* Ap = (t3 == 1) ? Plo : Phi;
    const hb* Bp = (t3 == 2) ? Elo : Ehi;
    for (int k0 = kbeg; k0 < kend; k0 += 64) {
#pragma unroll
      for (int it = 0; it < 2; ++it)
        gload16(Ap + aoff[it] + k0, &As[(tid + it * 256) * 8]);
#pragma unroll
      for (int it = 0; it < 3; ++it)
        gload16(Bp + boff[it] + k0, &Bs[(tid + it * 256) * 8]);
      __syncthreads();
#pragma unroll
      for (int ks = 0; ks < 2; ++ks) {
        short8 a[2], bb[3];
#pragma unroll
        for (int mi = 0; mi < 2; ++mi)
          a[mi] = *(const short8*)&As[(wr * 32 + mi * 16 + lrow) * 64 + ks * 32 + lk * 8];
#pragma unroll
        for (int ni = 0; ni < 3; ++ni)
          bb[ni] = *(const short8*)&Bs[(wc * 48 + ni * 16 + lrow) * 64 + ks * 32 + lk * 8];
#pragma unroll
        for (int mi = 0; mi < 2; ++mi)
#pragma unroll
          for (int ni = 0; ni < 3; ++ni)
            acc[mi][ni] = __builtin_amdgcn_mfma_f32_16x16x32_bf16(
                a[mi], bb[ni], acc[mi][ni], 0, 0, 0);
      }
      __syncthreads();
    }
  }

#pragma unroll
  for (int mi = 0; mi < 2; ++mi) {
#pragma unroll
    for (int ni = 0; ni < 3; ++ni) {
#pragma unroll
      for (int q = 0; q < 4; ++q) {
        int i = wr * 32 + mi * 16 + lk * 4 + q;
        int n = wc * 48 + ni * 16 + lrow;
        int d = n - i;
        if (d >= 0 && d < 32) {
          long long off = (((long long)(kq * 2 + b)) * S_LEN + (s0 + i)) * 32 + d;
          partial[off] = acc[mi][ni][q];
        }
      }
    }
  }
}

// sum partials (fixed order), add ssc/esc, clip; -3e38 outside band
__global__ __launch_bounds__(256) void band_reduce(
    const float* __restrict__ partial, const float* __restrict__ ssc,
    const float* __restrict__ esc, float* __restrict__ band)
{
  int idx = blockIdx.x * 256 + threadIdx.x;
  if (idx >= BATCH * S_LEN * 32) return;
  int d = idx & 31;
  int s = (idx >> 5) & (S_LEN - 1);
  int b = idx >> 16;
  int t = s + d;
  float v;
  if (d < MAXSPAN && t < S_LEN) {
    float sum = 0.f;
#pragma unroll
    for (int kq = 0; kq < 4; ++kq)
      sum += partial[(((long long)(kq * 2 + b)) * S_LEN + s) * 32 + d];
    sum += ssc[b * S_LEN + s] + esc[b * S_LEN + t];
    v = fminf(fmaxf(sum, NEGV), -NEGV);
  } else {
    v = -3.0e38f;
  }
  band[idx] = v;
}

// ---------------------------------------------------------------------------
// Merged prep: split emb f32 -> hi/lo bf16 (first nb_split blocks) AND
// split+transpose W f32 [K][N] -> hiT/loT bf16 [N][K] (remaining blocks).
// ---------------------------------------------------------------------------
__global__ __launch_bounds__(256) void prep_split(
    const float* __restrict__ emb, hb* __restrict__ hi, hb* __restrict__ lo,
    long long n4, int nb_split,
    const float* __restrict__ W, hb* __restrict__ WhiT, hb* __restrict__ WloT,
    int K, int N)
{
  if ((int)blockIdx.x < nb_split) {
    long long i = (long long)blockIdx.x * 256 + threadIdx.x;
    if (i >= n4) return;
    float4 v = ((const float4*)emb)[i];
    unsigned short h[4], l[4];
    float vv[4] = {v.x, v.y, v.z, v.w};
#pragma unroll
    for (int j = 0; j < 4; ++j) {
      h[j] = bf_bits(vv[j]);
      l[j] = bf_bits(vv[j] - bf_back(h[j]));
    }
    ((uint2*)hi)[i] = *(uint2*)h;
    ((uint2*)lo)[i] = *(uint2*)l;
    return;
  }
  __shared__ float t[32][33];
  int idx = blockIdx.x - nb_split;
  int xb = idx % (N / 32), yb = idx / (N / 32);
  int k0 = yb * 32, n0 = xb * 32;
  int tx = threadIdx.x & 31, ty = threadIdx.x >> 5;
#pragma unroll
  for (int r = 0; r < 4; ++r)
    t[ty + r * 8][tx] = W[(long long)(k0 + ty + r * 8) * N + (n0 + tx)];
  __syncthreads();
#pragma unroll
  for (int r = 0; r < 4; ++r) {
    int n = n0 + ty + r * 8;
    float v = t[tx][ty + r * 8];
    unsigned short h = bf_bits(v);
    unsigned short l = bf_bits(v - bf_back(h));
    WhiT[(long long)n * K + k0 + tx] = *reinterpret_cast<hb*>(&h);
    WloT[(long long)n * K + k0 + tx] = *reinterpret_cast<hb*>(&l);
  }
}

// split + transpose only (s2e_W, FDIM x FDIM)
__global__ __launch_bounds__(256) void splitT_mat(
    const float* __restrict__ src, hb* __restrict__ hiT, hb* __restrict__ loT,
    int K, int N)
{
  __shared__ float t[32][33];
  int k0 = blockIdx.y * 32, n0 = blockIdx.x * 32;
  int tx = threadIdx.x & 31, ty = threadIdx.x >> 5;
#pragma unroll
  for (int r = 0; r < 4; ++r)
    t[ty + r * 8][tx] = src[(long long)(k0 + ty + r * 8) * N + (n0 + tx)];
  __syncthreads();
#pragma unroll
  for (int r = 0; r < 4; ++r) {
    int n = n0 + ty + r * 8;
    float v = t[tx][ty + r * 8];
    unsigned short h = bf_bits(v);
    unsigned short l = bf_bits(v - bf_back(h));
    hiT[(long long)n * K + k0 + tx] = *reinterpret_cast<hb*>(&h);
    loT[(long long)n * K + k0 + tx] = *reinterpret_cast<hb*>(&l);
  }
}

// ---------------------------------------------------------------------------
// Fused LayerNorm (fp64 stats) + hi/lo bf16 split + cls row-dot (fp64 accum)
// ---------------------------------------------------------------------------
__global__ __launch_bounds__(256) void ln_split_dot(
    const float* __restrict__ src, hb* __restrict__ hi, hb* __restrict__ lo,
    const float* __restrict__ g, const float* __restrict__ be,
    const float* __restrict__ w, const float* __restrict__ wb,
    float* __restrict__ dot_out)
{
  __shared__ float row[FDIM];
  __shared__ double scr[4];
  __shared__ double sh_mu, sh_rstd;
  const long long r = blockIdx.x;
  const float* p = src + r * FDIM;
  const int tid = threadIdx.x;

  double s = 0.0;
#pragma unroll
  for (int pp = 0; pp < 3; ++pp) {
    int c4 = pp * 256 + tid;
    float4 v = *(const float4*)(p + c4 * 4);
    *(float4*)&row[c4 * 4] = v;
    s += (double)v.x + (double)v.y + (double)v.z + (double)v.w;
  }
#pragma unroll
  for (int off = 32; off; off >>= 1) s += __shfl_down(s, off, 64);
  if ((tid & 63) == 0) scr[tid >> 6] = s;
  __syncthreads();
  if (tid == 0) sh_mu = (scr[0] + scr[1] + scr[2] + scr[3]) / FDIM;
  __syncthreads();
  double mu = sh_mu;
  double vs = 0.0;
#pragma unroll
  for (int pp = 0; pp < 12; ++pp) {
    double d = (double)row[pp * 256 + tid] - mu;
    vs += d * d;
  }
#pragma unroll
  for (int off = 32; off; off >>= 1) vs += __shfl_down(vs, off, 64);
  __syncthreads();
  if ((tid & 63) == 0) scr[tid >> 6] = vs;
  __syncthreads();
  if (tid == 0)
    sh_rstd = 1.0 / sqrt((scr[0] + scr[1] + scr[2] + scr[3]) / FDIM + 1e-5);
  __syncthreads();
  double rstd = sh_rstd;

  double dot = 0.0;
#pragma unroll
  for (int pp = 0; pp < 3; ++pp) {
    int c4 = pp * 256 + tid;
    float4 gv = *(const float4*)(g + c4 * 4);
    float4 bv = *(const float4*)(be + c4 * 4);
    float4 wv = *(const float4*)(w + c4 * 4);
    float xv[4];
    *(float4*)xv = *(const float4*)&row[c4 * 4];
    unsigned short hh[4], ll[4];
    float gg[4] = {gv.x, gv.y, gv.z, gv.w};
    float bb[4] = {bv.x, bv.y, bv.z, bv.w};
    float ww[4] = {wv.x, wv.y, wv.z, wv.w};
#pragma unroll
    for (int j = 0; j < 4; ++j) {
      float val = (float)(((double)xv[j] - mu) * rstd * (double)gg[j] + (double)bb[j]);
      dot += (double)val * (double)ww[j];
      hh[j] = bf_bits(val);
      ll[j] = bf_bits(val - bf_back(hh[j]));
    }
    *(uint2*)(hi + r * FDIM + c4 * 4) = *(uint2*)hh;
    *(uint2*)(lo + r * FDIM + c4 * 4) = *(uint2*)ll;
  }
#pragma unroll
  for (int off = 32; off; off >>= 1) dot += __shfl_down(dot, off, 64);
  __syncthreads();
  if ((tid & 63) == 0) scr[tid >> 6] = dot;
  __syncthreads();
  if (tid == 0)
    dot_out[r] = (float)(scr[0] + scr[1] + scr[2] + scr[3] + (double)wb[0]);
}

// LayerNorm f32 src -> bf16 dst, y-batched pair (phase-2)
__global__ __launch_bounds__(256) void ln_rows_bf2(
    const float* __restrict__ src0, const float* __restrict__ src1,
    hb* __restrict__ dst0, hb* __restrict__ dst1,
    const float* __restrict__ g0, const float* __restrict__ g1,
    const float* __restrict__ be0, const float* __restrict__ be1,
    int n, long long lds_, long long ldd)
{
  const int sel = blockIdx.y;
  long long r = blockIdx.x;
  const float* p = (sel ? src1 : src0) + r * lds_;
  hb* d = (sel ? dst1 : dst0) + r * ldd;
  const float* g = sel ? g1 : g0;
  const float* be = sel ? be1 : be0;
  __shared__ double scratch[4];
  __shared__ double sh_mu, sh_rstd;
  double s = 0.0;
  for (int c = threadIdx.x; c < n; c += 256) s += (double)p[c];
#pragma unroll
  for (int off = 32; off; off >>= 1) s += __shfl_down(s, off, 64);
  if ((threadIdx.x & 63) == 0) scratch[threadIdx.x >> 6] = s;
  __syncthreads();
  if (threadIdx.x == 0) sh_mu = (scratch[0] + scratch[1] + scratch[2] + scratch[3]) / n;
  __syncthreads();
  double mu = sh_mu;
  double vs = 0.0;
  for (int c = threadIdx.x; c < n; c += 256) { double dd = (double)p[c] - mu; vs += dd * dd; }
#pragma unroll
  for (int off = 32; off; off >>= 1) vs += __shfl_down(vs, off, 64);
  __syncthreads();
  if ((threadIdx.x & 63) == 0) scratch[threadIdx.x >> 6] = vs;
  __syncthreads();
  if (threadIdx.x == 0)
    sh_rstd = 1.0 / sqrt((scratch[0] + scratch[1] + scratch[2] + scratch[3]) / n + 1e-5);
  __syncthreads();
  double rstd = sh_rstd;
  for (int c = threadIdx.x; c < n; c += 256)
    d[c] = __float2bfloat16(
        (float)(((double)p[c] - mu) * rstd * (double)g[c] + (double)be[c]));
}

// ---------------------------------------------------------------------------
// Top-k selection (radix on monotone float keys) + index sort, 1 block/batch.
// Scans are LINEAR over the padded [S_LEN][32] slab (float4, coalesced, no
// div). Pad columns (d>=30 / t>=S_LEN) hold -3e38: their keys are strictly
// below any clipped in-band value (>= -1e4), and kv <= 819 << 61005 real
// entries, so they can never be selected — they only inflate the bottom
// histogram bucket.
// ---------------------------------------------------------------------------
__device__ __forceinline__ unsigned f2k(float f) {
  unsigned u = __float_as_uint(f);
  return (u & 0x80000000u) ? ~u : (u | 0x80000000u);
}

__device__ void bitonic1024(int* a) {
  const int tid = threadIdx.x;
  for (int sz = 2; sz <= 1024; sz <<= 1) {
    for (int st = sz >> 1; st > 0; st >>= 1) {
      __syncthreads();
      int j = tid ^ st;
      if (j > tid) {
        int x = a[tid], y = a[j];
        bool asc = (tid & sz) == 0;
        if ((x > y) == asc) { a[tid] = y; a[j] = x; }
      }
    }
  }
  __syncthreads();
}

__global__ __launch_bounds__(1024) void select_sort(
    const float* __restrict__ band, const int* __restrict__ masks,
    int* __restrict__ sidx, int* __restrict__ starts, int* __restrict__ ends,
    float* __restrict__ tms, int* __restrict__ kvals)
{
  const int b = blockIdx.x;
  const int tid = threadIdx.x;
  __shared__ int hist[256];
  __shared__ int sel[1024];
  __shared__ int eq[1024];
  __shared__ int sred[16];
  __shared__ int cvar[4];
  __shared__ int cnt_gt, cnt_eq;

  int msum = 0;
  for (int i = tid; i < S_LEN; i += 1024) msum += masks[b * S_LEN + i];
#pragma unroll
  for (int off = 32; off; off >>= 1) msum += __shfl_down(msum, off, 64);
  if ((tid & 63) == 0) sred[tid >> 6] = msum;
  __syncthreads();
  if (tid == 0) {
    int t = 0;
    for (int w = 0; w < 16; ++w) t += sred[w];
    cvar[2] = t;
  }
  __syncthreads();
  int kv = (int)((float)cvar[2] * 0.4f);
  if (kv > MAXK) kv = MAXK;
  if (kv < 0) kv = 0;

  const float* bb = band + (long long)b * (S_LEN * 32);
  const float4* b4 = (const float4*)bb;
  const int N4 = S_LEN * 8;            // 16384 float4 covering padded slab
  unsigned prefix = 0u;
  int remaining = kv;

  if (kv > 0) {
    for (int byte = 3; byte >= 0; --byte) {
      if (tid < 256) hist[tid] = 0;
      __syncthreads();
      for (int i = tid; i < N4; i += 1024) {
        float4 v = b4[i];
        float vv[4] = {v.x, v.y, v.z, v.w};
#pragma unroll
        for (int j = 0; j < 4; ++j) {
          unsigned key = f2k(vv[j]);
          bool match = (byte == 3) ||
              ((key >> ((byte + 1) * 8)) == (prefix >> ((byte + 1) * 8)));
          if (match) atomicAdd(&hist[(key >> (byte * 8)) & 255], 1);
        }
      }
      __syncthreads();
      if (tid == 0) {
        int cum = 0, chosen = 255;
        for (int v = 255; v >= 0; --v) {
          int h = hist[v];
          if (cum + h >= remaining) { chosen = v; cvar[0] = remaining - cum; break; }
          cum += h;
        }
        cvar[1] = chosen;
      }
      __syncthreads();
      remaining = cvar[0];
      prefix |= ((unsigned)cvar[1]) << (byte * 8);
      __syncthreads();
    }
    if (tid == 0) { cnt_gt = 0; cnt_eq = 0; }
    __syncthreads();
    for (int i = tid; i < N4; i += 1024) {
      float4 v = b4[i];
      float vv[4] = {v.x, v.y, v.z, v.w};
#pragma unroll
      for (int j = 0; j < 4; ++j) {
        unsigned key = f2k(vv[j]);
        if (key < prefix) continue;
        int e = i * 4 + j;
        int s = e >> 5, d = e & 31;
        int flat = s * S_LEN + s + d;
        if (key > prefix) {
          int p = atomicAdd(&cnt_gt, 1);
          if (p < MAXK) sel[p] = flat;
        } else {
          int p = atomicAdd(&cnt_eq, 1);
          if (p < 1024) eq[p] = flat;
        }
      }
    }
    __syncthreads();
    int ngt = cnt_gt;
    int neq = cnt_eq; if (neq > 1024) neq = 1024;
    if (tid >= neq) eq[tid] = 0x7FFFFFFF;
    __syncthreads();
    bitonic1024(eq);
    int need = kv - ngt;
    if (tid < need) sel[ngt + tid] = eq[tid];
    __syncthreads();
  }
  if (tid >= kv && tid < MAXK) sel[tid] = S_LEN * S_LEN - 1;
  if (tid >= MAXK) sel[tid] = 0x7FFFFFFF;
  __syncthreads();
  bitonic1024(sel);
  if (tid < MAXK) {
    int idx = sel[tid];
    int s = idx >> 11;
    int t = idx & (S_LEN - 1);
    sidx[b * MAXK + tid] = idx;
    starts[b * MAXK + tid] = s;
    ends[b * MAXK + tid] = t;
    tms[b * MAXK + tid] = band[((long long)(b * S_LEN + s)) * 32 + (t - s)];
  }
  if (tid == 0) kvals[b] = kv;
}

// y-batched gather pair: y=0 rows0->dst0, y=1 rows1->dst1 (H = 1024)
__global__ __launch_bounds__(256) void gather_bf2(
    const float* __restrict__ src,
    const int* __restrict__ rows0, const int* __restrict__ rows1,
    hb* __restrict__ dst0, hb* __restrict__ dst1)
{
  int g = blockIdx.x;
  int b = g / MAXK;
  const int* rows = blockIdx.y ? rows1 : rows0;
  hb* dst = blockIdx.y ? dst1 : dst0;
  int r = rows[g];
  const float4* s4 = (const float4*)(src + ((long long)(b * S_LEN + r)) * HDIM);
  hb* d = dst + (long long)g * HDIM;
  float4 v = s4[threadIdx.x];
  d[threadIdx.x * 4 + 0] = __float2bfloat16(v.x);
  d[threadIdx.x * 4 + 1] = __float2bfloat16(v.y);
  d[threadIdx.x * 4 + 2] = __float2bfloat16(v.z);
  d[threadIdx.x * 4 + 3] = __float2bfloat16(v.w);
}

// ---------------------------------------------------------------------------
// Merged phase-2 weight prep, one node:
//  z in 0..3, y<96 : transpose+convert a_{ss,es,se,ee}_W -> Wq1t/Wq2t cat
//  z == 4, y<32  : transpose+convert sc_W -> scWt
//  z == 4, 32<=y<64 : transpose+convert ec_W -> ecWt
//  z == 4, y==64, x<24 : biasq cat = [a_ss_b+a_es_b | a_se_b+a_ee_b]
// (r4 crash fix: z<4 branch MUST guard y >= FDIM/32 — grid-y is FDIM/32+1
//  for the bias row, and an unguarded y=96 read a_*_W 38MB out of bounds.)
// ---------------------------------------------------------------------------
__global__ __launch_bounds__(256) void wprep(
    const float* __restrict__ a0W, const float* __restrict__ a1W,
    const float* __restrict__ a2W, const float* __restrict__ a3W,
    hb* __restrict__ Wq1t, hb* __restrict__ Wq2t,
    const float* __restrict__ scW, const float* __restrict__ ecW,
    hb* __restrict__ scWt, hb* __restrict__ ecWt,
    const float* __restrict__ b0, const float* __restrict__ b1,
    const float* __restrict__ b2, const float* __restrict__ b3,
    float* __restrict__ biasq)
{
  const int z = blockIdx.z;
  int tx = threadIdx.x & 31, ty = threadIdx.x >> 5;
  if (z < 4) {
    if ((int)blockIdx.y >= FDIM / 32) return;   // bias row is z==4 only
    __shared__ float t[32][33];
    const float* src = (z == 0) ? a0W : (z == 1) ? a1W : (z == 2) ? a2W : a3W;
    hb* dst = (z < 2) ? Wq1t : Wq2t;
    const int koff = (z & 1) * FDIM;
    int k0 = blockIdx.y * 32, n0 = blockIdx.x * 32;
#pragma unroll
    for (int r = 0; r < 4; ++r)
      t[ty + r * 8][tx] = src[(long long)(k0 + ty + r * 8) * FDIM + (n0 + tx)];
    __syncthreads();
#pragma unroll
    for (int r = 0; r < 4; ++r) {
      int n = n0 + ty + r * 8;
      dst[(long long)n * (2 * FDIM) + koff + k0 + tx] =
          __float2bfloat16(t[tx][ty + r * 8]);
    }
  } else {
    int yy = blockIdx.y;
    if (yy < 64) {
      __shared__ float t[32][33];
      const float* src = (yy < 32) ? scW : ecW;
      hb* dst = (yy < 32) ? scWt : ecWt;
      int k0 = (yy & 31) * 32, n0 = blockIdx.x * 32;
#pragma unroll
      for (int r = 0; r < 4; ++r)
        t[ty + r * 8][tx] = src[(long long)(k0 + ty + r * 8) * FDIM + (n0 + tx)];
      __syncthreads();
#pragma unroll
      for (int r = 0; r < 4; ++r) {
        int n = n0 + ty + r * 8;
        dst[(long long)n * HDIM + k0 + tx] = __float2bfloat16(t[tx][ty + r * 8]);
      }
    } else if (yy == 64 && blockIdx.x < 24) {
      int i = blockIdx.x * 256 + threadIdx.x;   // 0..6143
      if (i < FDIM) biasq[i] = b0[i] + b1[i];
      else          biasq[i] = b2[i - FDIM] + b3[i - FDIM];
    }
  }
}

// out[b,i,j] assembly: sum 4 coref K-slices + pair + anaphora mask, zero last col
__global__ __launch_bounds__(256) void final_assemble(
    const float* __restrict__ coref4, const float* __restrict__ tms,
    const int* __restrict__ kvals, float* __restrict__ out)
{
  const long long SL = (long long)MAXK * MAXK;   // slice stride
  int g = blockIdx.x;                   // b*MAXK + i
  int b = g / MAXK;
  int i = g - b * MAXK;
  int kv = kvals[b];
  float ti = tms[g];
  const float* crow = coref4 + (long long)(b * 4) * SL + (long long)i * MAXK;
  float* orow = out + (long long)b * MAXK * (MAXK + 1) + (long long)i * (MAXK + 1);
  for (int j = threadIdx.x; j < MAXK + 1; j += 256) {
    float v;
    if (j == MAXK) v = 0.f;
    else {
      float c = ((crow[j] + crow[j + SL]) + (crow[j + 2 * SL] + crow[j + 3 * SL]));
      v = ti + tms[b * MAXK + j] + c;
      if (!((j < i) && (i < kv))) v += NEGV;
      v = fminf(fmaxf(v, NEGV), -NEGV);
    }
    orow[j] = v;
  }
}

// ---------------------------------------------------------------------------
static inline void launch1(const hb* A, const hb* B,
    const float* bias, const float* bias2, void* C,
    int M, int N, int K, int lda, int ldb, int ldc,
    long long sA, long long sB, long long sC,
    int act, int out_mode, int zcount, int kspl, hipStream_t stream)
{
  dim3 grid((N + 127) / 128, (M + 127) / 128, zcount);
  gemm_fast1<<<grid, 256, 0, stream>>>(A, B, bias, bias2, C, M, N, K,
                                       lda, ldb, ldc, sA, sB, sC,
                                       act, out_mode, kspl);
}

static inline void launch3(const hb* Ah, const hb* Al, const hb* Bh, const hb* Bl,
    const float* bias, void* C, void* C2, int M, int N, int K,
    int lda, int ldb, int ldc, int act, int out_mode, hipStream_t stream)
{
  dim3 grid((N + 127) / 128, (M + 127) / 128, 1);
  gemm_fast3<<<grid, 256, 0, stream>>>(Ah, Al, Bh, Bl, bias, C, C2,
                                       M, N, K, lda, ldb, ldc, act, out_mode);
}

extern "C" void kernel_launch(void* const* d_in, const int* in_sizes, int n_in,
                              void* d_out, int out_size, void* d_ws, size_t ws_size,
                              hipStream_t stream) {
  const float* input_emb = (const float*)d_in[0];
  const int*   input_masks = (const int*)d_in[1];
  const float* sm_W = (const float*)d_in[2];
  const float* sm_b = (const float*)d_in[3];
  const float* sm_g = (const float*)d_in[4];
  const float* sm_be = (const float*)d_in[5];
  const float* em_W = (const float*)d_in[6];
  const float* em_b = (const float*)d_in[7];
  const float* em_g = (const float*)d_in[8];
  const float* em_be = (const float*)d_in[9];
  const float* sc_W = (const float*)d_in[10];
  const float* sc_b = (const float*)d_in[11];
  const float* sc_g = (const float*)d_in[12];
  const float* sc_be = (const float*)d_in[13];
  const float* ec_W = (const float*)d_in[14];
  const float* ec_b = (const float*)d_in[15];
  const float* ec_g = (const float*)d_in[16];
  const float* ec_be = (const float*)d_in[17];
  const float* cls_s_W = (const float*)d_in[18];
  const float* cls_s_b = (const float*)d_in[19];
  const float* cls_e_W = (const float*)d_in[20];
  const float* cls_e_b = (const float*)d_in[21];
  const float* s2e_W = (const float*)d_in[22];
  const float* s2e_b = (const float*)d_in[23];
  const float* a_ss_W = (const float*)d_in[24];
  const float* a_ss_b = (const float*)d_in[25];
  const float* a_ee_W = (const float*)d_in[26];
  const float* a_ee_b = (const float*)d_in[27];
  const float* a_se_W = (const float*)d_in[28];
  const float* a_se_b = (const float*)d_in[29];
  const float* a_es_W = (const float*)d_in[30];
  const float* a_es_b = (const float*)d_in[31];
  float* out = (float*)d_out;

  const int NROW = BATCH * S_LEN;           // 4096
  const int MROW = BATCH * MAXK;            // 1638
  const long long SZ_BIG = (long long)NROW * FDIM * 4;      // 50331648

  char* ws = (char*)d_ws;
  // ---- phase-1 regions (schedule in launch order) ----
  float* smF    = (float*)(ws);                     // sm f32, dead after LN
  hb* sm_hi     = (hb*)(ws + 50331648LL);
  hb* sm_lo     = (hb*)(ws + 75497472LL);
  hb* emb_hi    = (hb*)(ws + 100663296LL);
  hb* emb_lo    = (hb*)(ws + 109051904LL);
  hb* w1_hiT    = (hb*)(ws + 117440512LL);
  hb* w1_loT    = (hb*)(ws + 123731968LL);
  hb* s2e_hiT   = (hb*)(ws);                        // after smF dead
  hb* s2e_loT   = (hb*)(ws + 18874368LL);
  hb* proj_hi   = (hb*)(ws + 100663296LL);          // after emb/w1 dead
  hb* proj_lo   = (hb*)(ws + 125829120LL);
  hb* emb2_hi   = (hb*)(ws);                        // after s2eT dead
  hb* emb2_lo   = (hb*)(ws + 8388608LL);
  hb* w2_hiT    = (hb*)(ws + 16777216LL);
  hb* w2_loT    = (hb*)(ws + 23068672LL);
  float* emF    = (float*)(ws + 50331648LL);        // after sm splits dead
  hb* em_hi     = (hb*)(ws);                        // after emb2/w2 dead
  hb* em_lo     = (hb*)(ws + 25165824LL);
  float* partial = (float*)(ws + 50331648LL);       // after emF dead, 2 MB
  // ---- phase-2 overlay (re-planned r4 so all weights coexist -> 1 wprep) ----
  hb* Wq1t  = (hb*)(ws);                            // [3072][6144] cat rows 0..3071
  hb* Wq2t  = (hb*)(ws + 37748736LL);               // rows 3072..6143 (contig!)
  hb* tkcat = (hb*)(ws + 75497472LL);               // [1638][6144]
  hb* qcat  = (hb*)(ws + 95625216LL);               // live after mlp dead
  float* coref4 = (float*)(ws + 115752960LL);       // [2][4][819][819] f32
  float* mlp_s = (float*)(ws + 95625216LL);         // overlays future qcat
  float* mlp_e = (float*)(ws + 115752960LL);        // overlays future coref4
  hb* Xs_bf = (hb*)(ws + 75497472LL);               // inside future tkcat
  hb* Xe_bf = (hb*)(ws + 78852096LL);               //   (dead before tkcat write)
  hb* scWt  = (hb*)(ws + 82206720LL);
  hb* ecWt  = (hb*)(ws + 88498176LL);
  // ---- persistent tail ----
  const long long P = 3 * SZ_BIG;                   // 150994944
  float* band = (float*)(ws + P);
  float* ssc  = (float*)(ws + P + 524288);
  float* esc  = (float*)(ws + P + 540672);
  int* sidx   = (int*)(ws + P + 557056);
  int* starts = (int*)(ws + P + 565248);
  int* ends   = (int*)(ws + P + 573440);
  float* tms  = (float*)(ws + P + 581632);
  int* kvals  = (int*)(ws + P + 589824);
  float* biasq1 = (float*)(ws + P + 590080);        // [3072]
  float* biasq2 = (float*)(ws + P + 602368);        // contiguous -> [6144] cat
  (void)biasq2;
  if (ws_size < (size_t)(P + 614656)) return;

  const long long n4_emb = (long long)NROW * HDIM / 4;
  const int nb_split = (int)((n4_emb + 255) / 256);
  const int nb_T = (FDIM / 32) * (HDIM / 32);

  // ---- phase 1: selection-critical chain ----
  prep_split<<<nb_split + nb_T, 256, 0, stream>>>(
      input_emb, emb_hi, emb_lo, n4_emb, nb_split, sm_W, w1_hiT, w1_loT, HDIM, FDIM);
  launch3(emb_hi, emb_lo, w1_hiT, w1_loT, sm_b, smF, nullptr,
          NROW, FDIM, HDIM, HDIM, HDIM, FDIM, 1, 0, stream);
  ln_split_dot<<<NROW, 256, 0, stream>>>(smF, sm_hi, sm_lo, sm_g, sm_be,
                                         cls_s_W, cls_s_b, ssc);
  splitT_mat<<<dim3(FDIM / 32, FDIM / 32), 256, 0, stream>>>(s2e_W, s2e_hiT, s2e_loT, FDIM, FDIM);
  launch3(sm_hi, sm_lo, s2e_hiT, s2e_loT, s2e_b, proj_hi, proj_lo,
          NROW, FDIM, FDIM, FDIM, FDIM, FDIM, 0, 2, stream);
  prep_split<<<nb_split + nb_T, 256, 0, stream>>>(
      input_emb, emb2_hi, emb2_lo, n4_emb, nb_split, em_W, w2_hiT, w2_loT, HDIM, FDIM);
  launch3(emb2_hi, emb2_lo, w2_hiT, w2_loT, em_b, emF, nullptr,
          NROW, FDIM, HDIM, HDIM, HDIM, FDIM, 1, 0, stream);
  ln_split_dot<<<NROW, 256, 0, stream>>>(emF, em_hi, em_lo, em_g, em_be,
                                         cls_e_W, cls_e_b, esc);
  bandmm<<<dim3(S_LEN / 64, 4, BATCH), 256, 0, stream>>>(proj_hi, proj_lo, em_hi, em_lo, partial);
  band_reduce<<<(BATCH * S_LEN * 32) / 256, 256, 0, stream>>>(partial, ssc, esc, band);
  select_sort<<<BATCH, 1024, 0, stream>>>(band, input_masks, sidx, starts, ends, tms, kvals);

  // ---- phase 2 ----
  gather_bf2<<<dim3(MROW, 2), 256, 0, stream>>>(input_emb, starts, ends, Xs_bf, Xe_bf);

  wprep<<<dim3(FDIM / 32, FDIM / 32 + 1, 5), 256, 0, stream>>>(
      a_ss_W, a_es_W, a_se_W, a_ee_W, Wq1t, Wq2t,
      sc_W, ec_W, scWt, ecWt,
      a_ss_b, a_es_b, a_se_b, a_ee_b, biasq1);

  // batched mlp_s/mlp_e: z=2, contiguous operand strides, per-z bias
  launch1(Xs_bf, scWt, sc_b, ec_b, mlp_s, MROW, FDIM, HDIM, HDIM, HDIM, FDIM,
          (long long)MROW * HDIM, (long long)FDIM * HDIM, (long long)MROW * FDIM,
          1, 0, 2, 1, stream);

  ln_rows_bf2<<<dim3(MROW, 2), 256, 0, stream>>>(
      mlp_s, mlp_e, tkcat, tkcat + FDIM, sc_g, ec_g, sc_be, ec_be,
      FDIM, FDIM, 2 * FDIM);

  // fused qcat: N = 6144 over contiguous [Wq1t; Wq2t] and [biasq1|biasq2]
  launch1(tkcat, Wq1t, biasq1, nullptr, qcat, MROW, 2 * FDIM, 2 * FDIM,
          2 * FDIM, 2 * FDIM, 2 * FDIM, 0, 0, 0, 0, 1, 1, 1, stream);

  // coref: split-K x4 (K=1536/slice), batched z = b*4 + ks
  launch1(qcat, tkcat, nullptr, nullptr, coref4, MAXK, MAXK, 1536,
          2 * FDIM, 2 * FDIM, MAXK,
          (long long)MAXK * 2 * FDIM, (long long)MAXK * 2 * FDIM,
          (long long)MAXK * MAXK, 0, 0, BATCH * 4, 4, stream);

  final_assemble<<<MROW, 256, 0, stream>>>(coref4, tms, kvals, out);
}